// Round 1
// baseline (980.539 us; speedup 1.0000x reference)
//
#include <hip/hip_runtime.h>
#include <hip/hip_bf16.h>
#include <math.h>

typedef __bf16 bf16_t;
typedef __bf16 bf16x8 __attribute__((ext_vector_type(8)));
typedef __bf16 bf16x4 __attribute__((ext_vector_type(4)));
typedef float  f32x4  __attribute__((ext_vector_type(4)));

#define BM 128
#define BN 128
#define BK 32
#define LDSP 40   // padded row length (bf16 elems): 80B rows, 16B-aligned chunks

enum { BMODE_BT16 = 0, BMODE_T16 = 1 };
enum { EPI_BF16_BIAS = 0, EPI_F32_SCALE = 1, EPI_BF16 = 2, EPI_F32_BIAS_RES = 3, EPI_BF16_BIAS_GELU = 4 };

__device__ __forceinline__ float gelu_exact(float v) {
  return 0.5f * v * (1.0f + erff(v * 0.7071067811865476f));
}

// ---------------- GEMM ----------------
// C[M][N] = A[M][K] @ B ( + bias / residual / gelu ), bf16 MFMA, fp32 accum.
// BMODE_BT16: B given as [N][K] bf16 row-major (ldb = row stride) -> direct stage
// BMODE_T16 : B given as [K][N] bf16 row-major -> transpose during stage
template<int BMODE, int EPI>
__global__ __launch_bounds__(256) void tb_gemm(
    const bf16_t* __restrict__ A, int lda, long long strideA,
    const void*  __restrict__ Bp, int ldb, long long strideB,
    const float* __restrict__ bias,
    const float* __restrict__ resid,
    void* __restrict__ Cp, int ldc, long long strideC,
    int K, float scale)
{
  __shared__ bf16_t As[BM][LDSP];
  __shared__ bf16_t Bs[BN][LDSP];

  const int tid = threadIdx.x;
  const int z = blockIdx.z;
  const int m0 = blockIdx.y * BM;
  const int n0 = blockIdx.x * BN;

  const bf16_t* Az = A + (size_t)z * strideA;

  const int lane = tid & 63;
  const int wid  = tid >> 6;
  const int wrow = (wid >> 1) * 64;
  const int wcol = (wid & 1) * 64;
  const int lr = lane & 15;
  const int lg = lane >> 4;

  f32x4 acc[4][4];
#pragma unroll
  for (int m = 0; m < 4; ++m)
#pragma unroll
    for (int n = 0; n < 4; ++n)
      acc[m][n] = (f32x4){0.f, 0.f, 0.f, 0.f};

  for (int k0 = 0; k0 < K; k0 += BK) {
    // ---- stage A: 128 x 32 bf16, 512 chunks of 8 ----
#pragma unroll
    for (int i = 0; i < 2; ++i) {
      int c = tid + i * 256;
      int row = c >> 2;
      int kc = (c & 3) * 8;
      uint4 d = *(const uint4*)(Az + (size_t)(m0 + row) * lda + k0 + kc);
      *(uint4*)&As[row][kc] = d;
    }
    // ---- stage B ----
    if constexpr (BMODE == BMODE_BT16) {
      const bf16_t* B = (const bf16_t*)Bp + (size_t)z * strideB;
#pragma unroll
      for (int i = 0; i < 2; ++i) {
        int c = tid + i * 256;
        int n = c >> 2;
        int kc = (c & 3) * 8;
        uint4 d = *(const uint4*)(B + (size_t)(n0 + n) * ldb + k0 + kc);
        *(uint4*)&Bs[n][kc] = d;
      }
    } else {  // BMODE_T16: B[K][N] bf16, transpose into Bs[n][k]
      const bf16_t* B = (const bf16_t*)Bp + (size_t)z * strideB;
#pragma unroll
      for (int i = 0; i < 2; ++i) {
        int idx = tid + i * 256;
        int k = idx >> 4;          // 0..31
        int n8 = (idx & 15) * 8;   // 0..120
        bf16x8 d = *(const bf16x8*)(B + (size_t)(k0 + k) * ldb + n0 + n8);
#pragma unroll
        for (int j = 0; j < 8; ++j) Bs[n8 + j][k] = d[j];
      }
    }
    __syncthreads();

    bf16x8 a[4], b[4];
#pragma unroll
    for (int m = 0; m < 4; ++m) a[m] = *(const bf16x8*)&As[wrow + m * 16 + lr][lg * 8];
#pragma unroll
    for (int n = 0; n < 4; ++n) b[n] = *(const bf16x8*)&Bs[wcol + n * 16 + lr][lg * 8];
#pragma unroll
    for (int m = 0; m < 4; ++m)
#pragma unroll
      for (int n = 0; n < 4; ++n)
        acc[m][n] = __builtin_amdgcn_mfma_f32_16x16x32_bf16(a[m], b[n], acc[m][n], 0, 0, 0);
    __syncthreads();
  }

  // ---- epilogue ----
#pragma unroll
  for (int m = 0; m < 4; ++m) {
#pragma unroll
    for (int n = 0; n < 4; ++n) {
#pragma unroll
      for (int r = 0; r < 4; ++r) {
        int row = m0 + wrow + m * 16 + lg * 4 + r;
        int col = n0 + wcol + n * 16 + lr;
        float v = acc[m][n][r] * scale;
        if constexpr (EPI == EPI_BF16_BIAS || EPI == EPI_F32_BIAS_RES || EPI == EPI_BF16_BIAS_GELU)
          v += bias[col];
        if constexpr (EPI == EPI_BF16_BIAS_GELU)
          v = gelu_exact(v);
        if constexpr (EPI == EPI_F32_BIAS_RES)
          v += resid[(size_t)row * ldc + col];
        if constexpr (EPI == EPI_BF16_BIAS || EPI == EPI_BF16 || EPI == EPI_BF16_BIAS_GELU) {
          ((bf16_t*)Cp)[(size_t)z * strideC + (size_t)row * ldc + col] = (bf16_t)v;
        } else {
          ((float*)Cp)[(size_t)z * strideC + (size_t)row * ldc + col] = v;
        }
      }
    }
  }
}

// ---------------- transpose + cast f32[R][C] -> bf16[C][R] ----------------
__global__ __launch_bounds__(256) void tb_transpose_cast(
    const float* __restrict__ in, bf16_t* __restrict__ outT, int R, int C)
{
  __shared__ float tile[32][33];
  int c0 = blockIdx.x * 32;
  int r0 = blockIdx.y * 32;
  int t = threadIdx.x;
  int r = t >> 3;
  int c4 = (t & 7) * 4;
  float4 d = *(const float4*)(in + (size_t)(r0 + r) * C + c0 + c4);
  tile[r][c4 + 0] = d.x; tile[r][c4 + 1] = d.y; tile[r][c4 + 2] = d.z; tile[r][c4 + 3] = d.w;
  __syncthreads();
  int c = t >> 3;
  int r4 = (t & 7) * 4;
  bf16x4 o;
  o[0] = (bf16_t)tile[r4 + 0][c];
  o[1] = (bf16_t)tile[r4 + 1][c];
  o[2] = (bf16_t)tile[r4 + 2][c];
  o[3] = (bf16_t)tile[r4 + 3][c];
  *(bf16x4*)(outT + (size_t)(c0 + c) * R + r0 + r4) = o;
}

// ---------------- LayerNorm (fp32 in, bf16 out), one block per row of 2048 ----------------
__global__ __launch_bounds__(256) void tb_layernorm(
    const float* __restrict__ x, const float* __restrict__ g, const float* __restrict__ b,
    bf16_t* __restrict__ h)
{
  __shared__ float sa[4], sb[4];
  int row = blockIdx.x;
  int t = threadIdx.x;
  const float* xr = x + (size_t)row * 2048;
  float4 v0 = *(const float4*)(xr + t * 8);
  float4 v1 = *(const float4*)(xr + t * 8 + 4);
  float a[8] = {v0.x, v0.y, v0.z, v0.w, v1.x, v1.y, v1.z, v1.w};
  float s = 0.f, q = 0.f;
#pragma unroll
  for (int j = 0; j < 8; ++j) { s += a[j]; q += a[j] * a[j]; }
#pragma unroll
  for (int o = 32; o; o >>= 1) { s += __shfl_down(s, o); q += __shfl_down(q, o); }
  int w = t >> 6, l = t & 63;
  if (l == 0) { sa[w] = s; sb[w] = q; }
  __syncthreads();
  if (t == 0) {
    sa[0] = sa[0] + sa[1] + sa[2] + sa[3];
    sb[0] = sb[0] + sb[1] + sb[2] + sb[3];
  }
  __syncthreads();
  float mu = sa[0] * (1.0f / 2048.0f);
  float var = sb[0] * (1.0f / 2048.0f) - mu * mu;
  float rs = rsqrtf(var + 1e-5f);
  float4 g0 = *(const float4*)(g + t * 8);
  float4 g1 = *(const float4*)(g + t * 8 + 4);
  float4 b0 = *(const float4*)(b + t * 8);
  float4 b1 = *(const float4*)(b + t * 8 + 4);
  float gv[8] = {g0.x, g0.y, g0.z, g0.w, g1.x, g1.y, g1.z, g1.w};
  float bv[8] = {b0.x, b0.y, b0.z, b0.w, b1.x, b1.y, b1.z, b1.w};
  bf16x8 o8;
#pragma unroll
  for (int j = 0; j < 8; ++j) o8[j] = (bf16_t)((a[j] - mu) * rs * gv[j] + bv[j]);
  *(bf16x8*)(h + (size_t)row * 2048 + t * 8) = o8;
}

// ---------------- Softmax (fp32 in, bf16 out), one block per row of 2048 ----------------
__global__ __launch_bounds__(256) void tb_softmax(
    const float* __restrict__ S, bf16_t* __restrict__ P)
{
  __shared__ float sa[4];
  int row = blockIdx.x;
  int t = threadIdx.x;
  const float* sr = S + (size_t)row * 2048;
  float4 a0 = *(const float4*)(sr + t * 8);
  float4 a1 = *(const float4*)(sr + t * 8 + 4);
  float v[8] = {a0.x, a0.y, a0.z, a0.w, a1.x, a1.y, a1.z, a1.w};
  float m = v[0];
#pragma unroll
  for (int j = 1; j < 8; ++j) m = fmaxf(m, v[j]);
#pragma unroll
  for (int o = 32; o; o >>= 1) m = fmaxf(m, __shfl_down(m, o));
  int w = t >> 6, l = t & 63;
  if (l == 0) sa[w] = m;
  __syncthreads();
  if (t == 0) sa[0] = fmaxf(fmaxf(sa[0], sa[1]), fmaxf(sa[2], sa[3]));
  __syncthreads();
  m = sa[0];
  __syncthreads();  // before reusing sa
  float s = 0.f;
#pragma unroll
  for (int j = 0; j < 8; ++j) { v[j] = expf(v[j] - m); s += v[j]; }
#pragma unroll
  for (int o = 32; o; o >>= 1) s += __shfl_down(s, o);
  if (l == 0) sa[w] = s;
  __syncthreads();
  if (t == 0) sa[0] = sa[0] + sa[1] + sa[2] + sa[3];
  __syncthreads();
  float inv = 1.0f / sa[0];
  bf16x8 o8;
#pragma unroll
  for (int j = 0; j < 8; ++j) o8[j] = (bf16_t)(v[j] * inv);
  *(bf16x8*)(P + (size_t)row * 2048 + t * 8) = o8;
}

// ---------------- host ----------------
extern "C" void kernel_launch(void* const* d_in, const int* in_sizes, int n_in,
                              void* d_out, int out_size, void* d_ws, size_t ws_size,
                              hipStream_t stream) {
  const float* x     = (const float*)d_in[0];
  const float* ln1_g = (const float*)d_in[1];
  const float* ln1_b = (const float*)d_in[2];
  const float* ln2_g = (const float*)d_in[3];
  const float* ln2_b = (const float*)d_in[4];
  const float* qkv_w = (const float*)d_in[5];
  const float* qkv_b = (const float*)d_in[6];
  const float* out_w = (const float*)d_in[7];
  const float* out_b = (const float*)d_in[8];
  const float* w1    = (const float*)d_in[9];
  const float* b1    = (const float*)d_in[10];
  const float* w2    = (const float*)d_in[11];
  const float* b2    = (const float*)d_in[12];
  float* out = (float*)d_out;
  char* ws = (char*)d_ws;

  // workspace layout (bytes)
  bf16_t* qkv_wT = (bf16_t*)(ws + 0);           // [6144][2048] bf16 = 25,165,824
  bf16_t* out_wT = (bf16_t*)(ws + 25165824);    // [2048][2048] bf16 =  8,388,608
  bf16_t* w1T    = (bf16_t*)(ws + 33554432);    // [8192][2048] bf16 = 33,554,432
  bf16_t* w2T    = (bf16_t*)(ws + 67108864);    // [2048][8192] bf16 = 33,554,432
  bf16_t* h_bf   = (bf16_t*)(ws + 100663296);   // [4096][2048] bf16 = 16,777,216
  bf16_t* qkv_bf = (bf16_t*)(ws + 117440512);   // [4096][6144] bf16 = 50,331,648
  float*  scores = (float*)(ws + 167772160);    // [2][2048][2048] f32 = 33,554,432
  bf16_t* attn_bf= (bf16_t*)(ws + 201326592);   // [2][2048][2048] bf16 = 16,777,216
  bf16_t* ao_bf  = (bf16_t*)(ws + 218103808);   // [4096][2048] bf16 = 16,777,216
  float*  x2     = (float*)(ws + 234881024);    // [4096][2048] f32 = 33,554,432
  bf16_t* mid_bf = (bf16_t*)(ws + 117440512);   // alias qkv_bf+scores (dead by MLP1) 67,108,864
  // total footprint: 268,435,456 bytes

  const float inv_sqrt_h = 0.022097086912079608f; // 1/sqrt(2048)

  // 1) weight transposes (fp32 -> bf16 [N][K])
  tb_transpose_cast<<<dim3(6144 / 32, 2048 / 32), 256, 0, stream>>>(qkv_w, qkv_wT, 2048, 6144);
  tb_transpose_cast<<<dim3(2048 / 32, 2048 / 32), 256, 0, stream>>>(out_w, out_wT, 2048, 2048);
  tb_transpose_cast<<<dim3(8192 / 32, 2048 / 32), 256, 0, stream>>>(w1, w1T, 2048, 8192);
  tb_transpose_cast<<<dim3(2048 / 32, 8192 / 32), 256, 0, stream>>>(w2, w2T, 8192, 2048);

  // 2) LN1: x -> h_bf
  tb_layernorm<<<4096, 256, 0, stream>>>(x, ln1_g, ln1_b, h_bf);

  // 3) QKV: h_bf @ qkv_w + qkv_b -> qkv_bf  (M=4096, N=6144, K=2048)
  tb_gemm<BMODE_BT16, EPI_BF16_BIAS><<<dim3(48, 32, 1), 256, 0, stream>>>(
      h_bf, 2048, 0, qkv_wT, 2048, 0, qkv_b, nullptr, qkv_bf, 6144, 0, 2048, 1.0f);

  // 4) scores[z] = q[z] @ k[z]^T / sqrt(H)  (M=N=K=2048, z=2)
  tb_gemm<BMODE_BT16, EPI_F32_SCALE><<<dim3(16, 16, 2), 256, 0, stream>>>(
      qkv_bf, 6144, 2048LL * 6144, qkv_bf + 2048, 6144, 2048LL * 6144,
      nullptr, nullptr, scores, 2048, 2048LL * 2048, 2048, inv_sqrt_h);

  // 5) softmax rows -> attn_bf
  tb_softmax<<<4096, 256, 0, stream>>>(scores, attn_bf);

  // 6) PV: attn[z] @ v[z] -> ao_bf  (v is [K=t][N=h] -> transpose stage)
  tb_gemm<BMODE_T16, EPI_BF16><<<dim3(16, 16, 2), 256, 0, stream>>>(
      attn_bf, 2048, 2048LL * 2048, qkv_bf + 4096, 6144, 2048LL * 6144,
      nullptr, nullptr, ao_bf, 2048, 2048LL * 2048, 2048, 1.0f);

  // 7) out-proj + residual: x2 = x + ao_bf @ out_w + out_b  (M=4096, N=2048, K=2048)
  tb_gemm<BMODE_BT16, EPI_F32_BIAS_RES><<<dim3(16, 32, 1), 256, 0, stream>>>(
      ao_bf, 2048, 0, out_wT, 2048, 0, out_b, x, x2, 2048, 0, 2048, 1.0f);

  // 8) LN2: x2 -> h_bf (reuse)
  tb_layernorm<<<4096, 256, 0, stream>>>(x2, ln2_g, ln2_b, h_bf);

  // 9) MLP1 + GELU: mid_bf = gelu(h_bf @ w1 + b1)  (M=4096, N=8192, K=2048)
  tb_gemm<BMODE_BT16, EPI_BF16_BIAS_GELU><<<dim3(64, 32, 1), 256, 0, stream>>>(
      h_bf, 2048, 0, w1T, 2048, 0, b1, nullptr, mid_bf, 8192, 0, 2048, 1.0f);

  // 10) MLP2 + residual: out = x2 + mid_bf @ w2 + b2  (M=4096, N=2048, K=8192)
  tb_gemm<BMODE_BT16, EPI_F32_BIAS_RES><<<dim3(16, 32, 1), 256, 0, stream>>>(
      mid_bf, 8192, 0, w2T, 8192, 0, b2, x2, out, 2048, 0, 8192, 1.0f);
}

// Round 2
// 858.621 us; speedup vs baseline: 1.1420x; 1.1420x over previous
//
#include <hip/hip_runtime.h>
#include <hip/hip_bf16.h>
#include <math.h>

typedef __bf16 bf16_t;
typedef __bf16 bf16x8 __attribute__((ext_vector_type(8)));
typedef __bf16 bf16x4 __attribute__((ext_vector_type(4)));
typedef float  f32x4  __attribute__((ext_vector_type(4)));

enum { EPI_BF16_BIAS = 0, EPI_F32_SCALE = 1, EPI_BF16 = 2, EPI_F32_BIAS_RES = 3, EPI_BF16_BIAS_GELU = 4 };

__device__ __forceinline__ float gelu_exact(float v) {
  return 0.5f * v * (1.0f + erff(v * 0.7071067811865476f));
}

// HBM -> LDS direct copy, 16B per lane. LDS dest is wave-uniform base + lane*16.
__device__ __forceinline__ void gld_lds16(const bf16_t* g, bf16_t* l) {
  __builtin_amdgcn_global_load_lds(
      (const __attribute__((address_space(1))) uint32_t*)(uintptr_t)g,
      (__attribute__((address_space(3))) uint32_t*)(uintptr_t)l,
      16, 0, 0);
}

// ---------------- GEMM (m97 structure) ----------------
// C[M][N] = A[M][K] @ B^T ( + bias / residual / gelu ), bf16 MFMA, fp32 accum.
// A: [M][K] bf16 row-major (lda), B: [N][K] bf16 row-major (ldb).
// 128x128 tile, BK=32, 4 waves, 4x4 16x16x32 MFMA per wave, global_load_lds staging.
template<int EPI>
__global__ __launch_bounds__(256) void tb_gemm(
    const bf16_t* __restrict__ A, int lda, long long strideA,
    const bf16_t* __restrict__ B, int ldb, long long strideB,
    const float* __restrict__ bias,
    const float* __restrict__ resid,
    void* __restrict__ Cp, int ldc, long long strideC,
    int K, float scale)
{
  __shared__ bf16_t As[128 * 32];  // linear [row][k], 64B rows (gload_lds needs linear dest)
  __shared__ bf16_t Bs[128 * 32];

  const int tid = threadIdx.x;
  const int z = blockIdx.z;
  const int m0 = blockIdx.y * 128;
  const int n0 = blockIdx.x * 128;

  const bf16_t* Az = A + (size_t)z * strideA;
  const bf16_t* Bz = B + (size_t)z * strideB;

  const int lane = tid & 63;
  const int wid  = tid >> 6;
  const int wrow = (wid >> 1) * 64;
  const int wcol = (wid & 1) * 64;
  const int lr = lane & 15;
  const int lg = lane >> 4;

  // staging geometry: chunk = 16 rows (1024B); lane covers 16B at row=lane>>2, kc=(lane&3)*8
  const int srow = lane >> 2;
  const int skc  = (lane & 3) * 8;

  f32x4 acc[4][4];
#pragma unroll
  for (int m = 0; m < 4; ++m)
#pragma unroll
    for (int n = 0; n < 4; ++n)
      acc[m][n] = (f32x4){0.f, 0.f, 0.f, 0.f};

  for (int k0 = 0; k0 < K; k0 += 32) {
#pragma unroll
    for (int i = 0; i < 2; ++i) {
      int chunk = wid * 2 + i;               // wave-uniform, 0..7
      int row = chunk * 16 + srow;
      gld_lds16(Az + (size_t)(m0 + row) * lda + k0 + skc, &As[chunk * 512 + lane * 8]);
    }
#pragma unroll
    for (int i = 0; i < 2; ++i) {
      int chunk = wid * 2 + i;
      int row = chunk * 16 + srow;
      gld_lds16(Bz + (size_t)(n0 + row) * ldb + k0 + skc, &Bs[chunk * 512 + lane * 8]);
    }
    __syncthreads();   // drains vmcnt -> staged data visible

    bf16x8 a[4], b[4];
#pragma unroll
    for (int m = 0; m < 4; ++m) a[m] = *(const bf16x8*)&As[(wrow + m * 16 + lr) * 32 + lg * 8];
#pragma unroll
    for (int n = 0; n < 4; ++n) b[n] = *(const bf16x8*)&Bs[(wcol + n * 16 + lr) * 32 + lg * 8];
#pragma unroll
    for (int m = 0; m < 4; ++m)
#pragma unroll
      for (int n = 0; n < 4; ++n)
        acc[m][n] = __builtin_amdgcn_mfma_f32_16x16x32_bf16(a[m], b[n], acc[m][n], 0, 0, 0);
    __syncthreads();   // protect LDS before next stage
  }

  // ---- epilogue ----
#pragma unroll
  for (int m = 0; m < 4; ++m) {
#pragma unroll
    for (int n = 0; n < 4; ++n) {
#pragma unroll
      for (int r = 0; r < 4; ++r) {
        int row = m0 + wrow + m * 16 + lg * 4 + r;
        int col = n0 + wcol + n * 16 + lr;
        float v = acc[m][n][r] * scale;
        if constexpr (EPI == EPI_BF16_BIAS || EPI == EPI_F32_BIAS_RES || EPI == EPI_BF16_BIAS_GELU)
          v += bias[col];
        if constexpr (EPI == EPI_BF16_BIAS_GELU)
          v = gelu_exact(v);
        if constexpr (EPI == EPI_F32_BIAS_RES)
          v += resid[(size_t)row * ldc + col];
        if constexpr (EPI == EPI_BF16_BIAS || EPI == EPI_BF16 || EPI == EPI_BF16_BIAS_GELU) {
          ((bf16_t*)Cp)[(size_t)z * strideC + (size_t)row * ldc + col] = (bf16_t)v;
        } else {
          ((float*)Cp)[(size_t)z * strideC + (size_t)row * ldc + col] = v;
        }
      }
    }
  }
}

// ---------------- transpose + cast f32[R][C] -> bf16[C][R] ----------------
__global__ __launch_bounds__(256) void tb_transpose_cast(
    const float* __restrict__ in, bf16_t* __restrict__ outT, int R, int C)
{
  __shared__ float tile[32][33];
  int c0 = blockIdx.x * 32;
  int r0 = blockIdx.y * 32;
  int t = threadIdx.x;
  int r = t >> 3;
  int c4 = (t & 7) * 4;
  float4 d = *(const float4*)(in + (size_t)(r0 + r) * C + c0 + c4);
  tile[r][c4 + 0] = d.x; tile[r][c4 + 1] = d.y; tile[r][c4 + 2] = d.z; tile[r][c4 + 3] = d.w;
  __syncthreads();
  int c = t >> 3;
  int r4 = (t & 7) * 4;
  bf16x4 o;
  o[0] = (bf16_t)tile[r4 + 0][c];
  o[1] = (bf16_t)tile[r4 + 1][c];
  o[2] = (bf16_t)tile[r4 + 2][c];
  o[3] = (bf16_t)tile[r4 + 3][c];
  *(bf16x4*)(outT + (size_t)(c0 + c) * R + r0 + r4) = o;
}

// ---------------- transpose bf16 [R][C](ldin) -> bf16 [C][R](ldout), batched ----------------
__global__ __launch_bounds__(256) void tb_transpose_bf16(
    const bf16_t* __restrict__ in, int ldin, long long sIn,
    bf16_t* __restrict__ out, int ldout, long long sOut)
{
  __shared__ bf16_t tile[32][40];
  int z = blockIdx.z;
  const bf16_t* src = in + (size_t)z * sIn;
  bf16_t* dst = out + (size_t)z * sOut;
  int c0 = blockIdx.x * 32;
  int r0 = blockIdx.y * 32;
  int t = threadIdx.x;
  int r = t >> 3;
  int c4 = (t & 7) * 4;
  bf16x4 d = *(const bf16x4*)(src + (size_t)(r0 + r) * ldin + c0 + c4);
  *(bf16x4*)&tile[r][c4] = d;
  __syncthreads();
  int c = t >> 3;
  int r4 = (t & 7) * 4;
  bf16x4 o;
  o[0] = tile[r4 + 0][c];
  o[1] = tile[r4 + 1][c];
  o[2] = tile[r4 + 2][c];
  o[3] = tile[r4 + 3][c];
  *(bf16x4*)(dst + (size_t)(c0 + c) * ldout + r0 + r4) = o;
}

// ---------------- LayerNorm (fp32 in, bf16 out), one block per row of 2048 ----------------
__global__ __launch_bounds__(256) void tb_layernorm(
    const float* __restrict__ x, const float* __restrict__ g, const float* __restrict__ b,
    bf16_t* __restrict__ h)
{
  __shared__ float sa[4], sb[4];
  int row = blockIdx.x;
  int t = threadIdx.x;
  const float* xr = x + (size_t)row * 2048;
  float4 v0 = *(const float4*)(xr + t * 8);
  float4 v1 = *(const float4*)(xr + t * 8 + 4);
  float a[8] = {v0.x, v0.y, v0.z, v0.w, v1.x, v1.y, v1.z, v1.w};
  float s = 0.f, q = 0.f;
#pragma unroll
  for (int j = 0; j < 8; ++j) { s += a[j]; q += a[j] * a[j]; }
#pragma unroll
  for (int o = 32; o; o >>= 1) { s += __shfl_down(s, o); q += __shfl_down(q, o); }
  int w = t >> 6, l = t & 63;
  if (l == 0) { sa[w] = s; sb[w] = q; }
  __syncthreads();
  if (t == 0) {
    sa[0] = sa[0] + sa[1] + sa[2] + sa[3];
    sb[0] = sb[0] + sb[1] + sb[2] + sb[3];
  }
  __syncthreads();
  float mu = sa[0] * (1.0f / 2048.0f);
  float var = sb[0] * (1.0f / 2048.0f) - mu * mu;
  float rs = rsqrtf(var + 1e-5f);
  float4 g0 = *(const float4*)(g + t * 8);
  float4 g1 = *(const float4*)(g + t * 8 + 4);
  float4 b0 = *(const float4*)(b + t * 8);
  float4 b1 = *(const float4*)(b + t * 8 + 4);
  float gv[8] = {g0.x, g0.y, g0.z, g0.w, g1.x, g1.y, g1.z, g1.w};
  float bv[8] = {b0.x, b0.y, b0.z, b0.w, b1.x, b1.y, b1.z, b1.w};
  bf16x8 o8;
#pragma unroll
  for (int j = 0; j < 8; ++j) o8[j] = (bf16_t)((a[j] - mu) * rs * gv[j] + bv[j]);
  *(bf16x8*)(h + (size_t)row * 2048 + t * 8) = o8;
}

// ---------------- Softmax (fp32 in, bf16 out), one block per row of 2048 ----------------
__global__ __launch_bounds__(256) void tb_softmax(
    const float* __restrict__ S, bf16_t* __restrict__ P)
{
  __shared__ float sa[4];
  int row = blockIdx.x;
  int t = threadIdx.x;
  const float* sr = S + (size_t)row * 2048;
  float4 a0 = *(const float4*)(sr + t * 8);
  float4 a1 = *(const float4*)(sr + t * 8 + 4);
  float v[8] = {a0.x, a0.y, a0.z, a0.w, a1.x, a1.y, a1.z, a1.w};
  float m = v[0];
#pragma unroll
  for (int j = 1; j < 8; ++j) m = fmaxf(m, v[j]);
#pragma unroll
  for (int o = 32; o; o >>= 1) m = fmaxf(m, __shfl_down(m, o));
  int w = t >> 6, l = t & 63;
  if (l == 0) sa[w] = m;
  __syncthreads();
  if (t == 0) sa[0] = fmaxf(fmaxf(sa[0], sa[1]), fmaxf(sa[2], sa[3]));
  __syncthreads();
  m = sa[0];
  __syncthreads();
  float s = 0.f;
#pragma unroll
  for (int j = 0; j < 8; ++j) { v[j] = expf(v[j] - m); s += v[j]; }
#pragma unroll
  for (int o = 32; o; o >>= 1) s += __shfl_down(s, o);
  if (l == 0) sa[w] = s;
  __syncthreads();
  if (t == 0) sa[0] = sa[0] + sa[1] + sa[2] + sa[3];
  __syncthreads();
  float inv = 1.0f / sa[0];
  bf16x8 o8;
#pragma unroll
  for (int j = 0; j < 8; ++j) o8[j] = (bf16_t)(v[j] * inv);
  *(bf16x8*)(P + (size_t)row * 2048 + t * 8) = o8;
}

// ---------------- host ----------------
extern "C" void kernel_launch(void* const* d_in, const int* in_sizes, int n_in,
                              void* d_out, int out_size, void* d_ws, size_t ws_size,
                              hipStream_t stream) {
  const float* x     = (const float*)d_in[0];
  const float* ln1_g = (const float*)d_in[1];
  const float* ln1_b = (const float*)d_in[2];
  const float* ln2_g = (const float*)d_in[3];
  const float* ln2_b = (const float*)d_in[4];
  const float* qkv_w = (const float*)d_in[5];
  const float* qkv_b = (const float*)d_in[6];
  const float* out_w = (const float*)d_in[7];
  const float* out_b = (const float*)d_in[8];
  const float* w1    = (const float*)d_in[9];
  const float* b1    = (const float*)d_in[10];
  const float* w2    = (const float*)d_in[11];
  const float* b2    = (const float*)d_in[12];
  float* out = (float*)d_out;
  char* ws = (char*)d_ws;

  // workspace layout (bytes), total 268,435,456
  bf16_t* qkv_wT = (bf16_t*)(ws + 0);           // [6144][2048] bf16 = 25,165,824
  bf16_t* out_wT = (bf16_t*)(ws + 25165824);    // [2048][2048] bf16 =  8,388,608
  bf16_t* w1T    = (bf16_t*)(ws + 33554432);    // [8192][2048] bf16 = 33,554,432
  bf16_t* w2T    = (bf16_t*)(ws + 67108864);    // [2048][8192] bf16 = 33,554,432
  bf16_t* h_bf   = (bf16_t*)(ws + 100663296);   // [4096][2048] bf16 = 16,777,216
  bf16_t* qkv_bf = (bf16_t*)(ws + 117440512);   // [4096][6144] bf16 = 50,331,648
  float*  scores = (float*)(ws + 167772160);    // [2][2048][2048] f32 = 33,554,432
  bf16_t* attn_bf= (bf16_t*)(ws + 201326592);   // [2][2048][2048] bf16 = 16,777,216
  bf16_t* ao_bf  = (bf16_t*)(ws + 218103808);   // [4096][2048] bf16 = 16,777,216
  float*  x2     = (float*)(ws + 234881024);    // [4096][2048] f32 = 33,554,432
  bf16_t* mid_bf = (bf16_t*)(ws + 117440512);   // alias qkv_bf+scores (dead by MLP1)
  bf16_t* Vt     = (bf16_t*)(ws + 234881024);   // [2][2048][2048] bf16, aliases x2 (dead by step 7)

  const float inv_sqrt_h = 0.022097086912079608f; // 1/sqrt(2048)

  // 1) weight transposes (fp32 -> bf16 [N][K])
  tb_transpose_cast<<<dim3(6144 / 32, 2048 / 32), 256, 0, stream>>>(qkv_w, qkv_wT, 2048, 6144);
  tb_transpose_cast<<<dim3(2048 / 32, 2048 / 32), 256, 0, stream>>>(out_w, out_wT, 2048, 2048);
  tb_transpose_cast<<<dim3(8192 / 32, 2048 / 32), 256, 0, stream>>>(w1, w1T, 2048, 8192);
  tb_transpose_cast<<<dim3(2048 / 32, 8192 / 32), 256, 0, stream>>>(w2, w2T, 8192, 2048);

  // 2) LN1: x -> h_bf
  tb_layernorm<<<4096, 256, 0, stream>>>(x, ln1_g, ln1_b, h_bf);

  // 3) QKV: h_bf @ qkv_w + qkv_b -> qkv_bf  (M=4096, N=6144, K=2048)
  tb_gemm<EPI_BF16_BIAS><<<dim3(48, 32, 1), 256, 0, stream>>>(
      h_bf, 2048, 0, qkv_wT, 2048, 0, qkv_b, nullptr, qkv_bf, 6144, 0, 2048, 1.0f);

  // 4) V transpose: qkv_bf[z][t][4096+h] -> Vt[z][h][t]
  tb_transpose_bf16<<<dim3(64, 64, 2), 256, 0, stream>>>(
      qkv_bf + 4096, 6144, 2048LL * 6144, Vt, 2048, 2048LL * 2048);

  // 5) scores[z] = q[z] @ k[z]^T / sqrt(H)  (M=N=K=2048, z=2); K matrix is [N=t][K=h] naturally
  tb_gemm<EPI_F32_SCALE><<<dim3(16, 16, 2), 256, 0, stream>>>(
      qkv_bf, 6144, 2048LL * 6144, qkv_bf + 2048, 6144, 2048LL * 6144,
      nullptr, nullptr, scores, 2048, 2048LL * 2048, 2048, inv_sqrt_h);

  // 6) softmax rows -> attn_bf
  tb_softmax<<<4096, 256, 0, stream>>>(scores, attn_bf);

  // 7) PV: attn[z] @ v[z] -> ao_bf ; B = Vt[z] is [N=h][K=t]
  tb_gemm<EPI_BF16><<<dim3(16, 16, 2), 256, 0, stream>>>(
      attn_bf, 2048, 2048LL * 2048, Vt, 2048, 2048LL * 2048,
      nullptr, nullptr, ao_bf, 2048, 2048LL * 2048, 2048, 1.0f);

  // 8) out-proj + residual: x2 = x + ao_bf @ out_w + out_b  (M=4096, N=2048, K=2048)
  tb_gemm<EPI_F32_BIAS_RES><<<dim3(16, 32, 1), 256, 0, stream>>>(
      ao_bf, 2048, 0, out_wT, 2048, 0, out_b, x, x2, 2048, 0, 2048, 1.0f);

  // 9) LN2: x2 -> h_bf (reuse)
  tb_layernorm<<<4096, 256, 0, stream>>>(x2, ln2_g, ln2_b, h_bf);

  // 10) MLP1 + GELU: mid_bf = gelu(h_bf @ w1 + b1)  (M=4096, N=8192, K=2048)
  tb_gemm<EPI_BF16_BIAS_GELU><<<dim3(64, 32, 1), 256, 0, stream>>>(
      h_bf, 2048, 0, w1T, 2048, 0, b1, nullptr, mid_bf, 8192, 0, 2048, 1.0f);

  // 11) MLP2 + residual: out = x2 + mid_bf @ w2 + b2  (M=4096, N=2048, K=8192)
  tb_gemm<EPI_F32_BIAS_RES><<<dim3(16, 32, 1), 256, 0, stream>>>(
      mid_bf, 8192, 0, w2T, 8192, 0, b2, x2, out, 2048, 0, 8192, 1.0f);
}

// Round 3
// 791.442 us; speedup vs baseline: 1.2389x; 1.0849x over previous
//
#include <hip/hip_runtime.h>
#include <hip/hip_bf16.h>
#include <math.h>

typedef __bf16 bf16_t;
typedef __bf16 bf16x8 __attribute__((ext_vector_type(8)));
typedef __bf16 bf16x4 __attribute__((ext_vector_type(4)));
typedef float  f32x4  __attribute__((ext_vector_type(4)));

enum { EPI_BF16_BIAS = 0, EPI_F32_SCALE = 1, EPI_BF16 = 2, EPI_F32_BIAS_RES = 3, EPI_BF16_BIAS_GELU = 4 };

__device__ __forceinline__ float gelu_exact(float v) {
  return 0.5f * v * (1.0f + erff(v * 0.7071067811865476f));
}

__device__ __forceinline__ void gld_lds16(const bf16_t* g, bf16_t* l) {
  __builtin_amdgcn_global_load_lds(
      (const __attribute__((address_space(1))) uint32_t*)(uintptr_t)g,
      (__attribute__((address_space(3))) uint32_t*)(uintptr_t)l, 16, 0, 0);
}

#define PH_BARRIER() do { __builtin_amdgcn_s_barrier(); __builtin_amdgcn_sched_barrier(0); } while(0)
#define LGKM0() do { asm volatile("s_waitcnt lgkmcnt(0)" ::: "memory"); __builtin_amdgcn_sched_barrier(0); } while(0)
#define VMCNT4() asm volatile("s_waitcnt vmcnt(4)" ::: "memory")
#define VMCNT0() asm volatile("s_waitcnt vmcnt(0)" ::: "memory")

// swizzled LDS read: 16B frag at (rowbase+lr, k-slot (ks*4+lg) XOR (lr&7))
#define RD(base, rowbase, ks) \
  (*(const bf16x8*)((base) + ((rowbase) + lr) * 64 + (((((ks) << 2) | lg)) ^ (lr & 7)) * 8))

#define DO_MFMA(IBASE, JBASE) \
  __builtin_amdgcn_s_setprio(1); \
  { _Pragma("unroll") for (int ii = 0; ii < 4; ++ii) \
    _Pragma("unroll") for (int jj = 0; jj < 2; ++jj) \
    _Pragma("unroll") for (int ks = 0; ks < 2; ++ks) \
      acc[(IBASE)+ii][(JBASE)+jj] = __builtin_amdgcn_mfma_f32_16x16x32_bf16( \
          aF[ii][ks], bF[jj][ks], acc[(IBASE)+ii][(JBASE)+jj], 0, 0, 0); } \
  __builtin_amdgcn_s_setprio(0);

// ---------------- GEMM: 256x256 tile, BK=64, 8 waves, 4-phase counted-vmcnt pipeline ----
// C[M][N] = A[M][K] @ B^T (+ epilogue). A:[M][K] bf16 (lda), B:[N][K] bf16 (ldb).
// M,N multiples of 256; K multiple of 64.
template<int EPI>
__global__ __launch_bounds__(512, 2) void tb_gemm8(
    const bf16_t* __restrict__ A, int lda, long long strideA,
    const bf16_t* __restrict__ B, int ldb, long long strideB,
    const float* __restrict__ bias,
    const float* __restrict__ resid,
    void* __restrict__ Cp, int ldc, long long strideC,
    int K, float scale)
{
  __shared__ __align__(16) bf16_t sm[65536];  // 128 KiB: buf{0,1} x (A 16384 + B 16384 elems)

  const int tid = threadIdx.x;
  const int lane = tid & 63;
  const int wid = tid >> 6;
  const int wm = wid >> 2;   // 0..1  (M wave group, interleaved at 16-row granularity)
  const int wn = wid & 3;    // 0..3  (N wave group)
  const int lr = lane & 15;
  const int lg = lane >> 4;
  const int z = blockIdx.z;
  const int m0 = blockIdx.y * 256;
  const int n0 = blockIdx.x * 256;

  const bf16_t* Ag = A + (size_t)z * strideA;
  const bf16_t* Bg = B + (size_t)z * strideB;

  const int l3 = lane >> 3;                 // row-within-chunk
  const int sl8 = ((lane & 7) ^ l3) << 3;   // inverse-swizzled source col (elems)

  f32x4 acc[8][4];
#pragma unroll
  for (int i = 0; i < 8; ++i)
#pragma unroll
    for (int j = 0; j < 4; ++j) acc[i][j] = (f32x4){0.f, 0.f, 0.f, 0.f};

  // stage half H (0: rows/cols 0-127, 1: 128-255) of A and B tiles for k-offset kt
  // into buffer based at (da, db). 4 gload_lds issues per wave. LDS dest linear;
  // global source column pre-permuted with the read swizzle (involution).
  auto stage = [&](bf16_t* da, bf16_t* db, int kt, int H) {
#pragma unroll
    for (int q = 0; q < 2; ++q) {
      int c = (wid << 1) + q;                 // chunk 0..15
      int row = (H << 7) + (c << 3) + l3;     // tile-local row
      gld_lds16(Ag + (size_t)(m0 + row) * lda + kt + sl8, da + (H << 13) + (c << 9) + lane * 8);
      gld_lds16(Bg + (size_t)(n0 + row) * ldb + kt + sl8, db + (H << 13) + (c << 9) + lane * 8);
    }
  };

  const int NT = K >> 6;
  // prologue: stage tile 0 (both halves) into buf0 -> 8 loads in flight
  stage(sm, sm + 16384, 0, 0);
  stage(sm, sm + 16384, 0, 1);

  bf16x8 aF[4][2], bF[2][2];

  for (int t = 0; t < NT; ++t) {
    bf16_t* cura = sm + ((t & 1) << 15);
    bf16_t* curb = cura + 16384;
    bf16_t* nxta = sm + (((t + 1) & 1) << 15);
    bf16_t* nxtb = nxta + 16384;
    const int ktn = (t + 1) << 6;
    const bool lastt = (t == NT - 1);

    // ---- phase 0: quadrant (mh0, nh0); stage half0(t+1); needs h0(t) done ----
    VMCNT4();
    PH_BARRIER();
#pragma unroll
    for (int ii = 0; ii < 4; ++ii) {
      aF[ii][0] = RD(cura, ii * 32 + wm * 16, 0);
      aF[ii][1] = RD(cura, ii * 32 + wm * 16, 1);
    }
#pragma unroll
    for (int jj = 0; jj < 2; ++jj) {
      bF[jj][0] = RD(curb, jj * 64 + wn * 16, 0);
      bF[jj][1] = RD(curb, jj * 64 + wn * 16, 1);
    }
    if (!lastt) stage(nxta, nxtb, ktn, 0);
    LGKM0();
    DO_MFMA(0, 0);

    // ---- phase 1: quadrant (mh0, nh1); stage half1(t+1); needs h1(t) done ----
    if (lastt) { VMCNT0(); } else { VMCNT4(); }
    PH_BARRIER();
#pragma unroll
    for (int jj = 0; jj < 2; ++jj) {
      bF[jj][0] = RD(curb, 128 + jj * 64 + wn * 16, 0);
      bF[jj][1] = RD(curb, 128 + jj * 64 + wn * 16, 1);
    }
    if (!lastt) stage(nxta, nxtb, ktn, 1);
    LGKM0();
    DO_MFMA(0, 2);

    // ---- phase 2: quadrant (mh1, nh1) ----
    PH_BARRIER();
#pragma unroll
    for (int ii = 0; ii < 4; ++ii) {
      aF[ii][0] = RD(cura, 128 + ii * 32 + wm * 16, 0);
      aF[ii][1] = RD(cura, 128 + ii * 32 + wm * 16, 1);
    }
    LGKM0();
    DO_MFMA(4, 2);

    // ---- phase 3: quadrant (mh1, nh0) ----
    PH_BARRIER();
#pragma unroll
    for (int jj = 0; jj < 2; ++jj) {
      bF[jj][0] = RD(curb, jj * 64 + wn * 16, 0);
      bF[jj][1] = RD(curb, jj * 64 + wn * 16, 1);
    }
    LGKM0();
    DO_MFMA(4, 0);
  }

  // ---- epilogue ----
#pragma unroll
  for (int i = 0; i < 8; ++i) {
    const int mr = ((i >> 2) << 7) + ((i & 3) << 5) + (wm << 4);
#pragma unroll
    for (int j = 0; j < 4; ++j) {
      const int nc = ((j >> 1) << 7) + ((j & 1) << 6) + (wn << 4);
#pragma unroll
      for (int r = 0; r < 4; ++r) {
        int row = m0 + mr + lg * 4 + r;
        int col = n0 + nc + lr;
        float v = acc[i][j][r] * scale;
        if constexpr (EPI == EPI_BF16_BIAS || EPI == EPI_F32_BIAS_RES || EPI == EPI_BF16_BIAS_GELU)
          v += bias[col];
        if constexpr (EPI == EPI_BF16_BIAS_GELU)
          v = gelu_exact(v);
        if constexpr (EPI == EPI_F32_BIAS_RES)
          v += resid[(size_t)row * ldc + col];
        if constexpr (EPI == EPI_BF16_BIAS || EPI == EPI_BF16 || EPI == EPI_BF16_BIAS_GELU) {
          ((bf16_t*)Cp)[(size_t)z * strideC + (size_t)row * ldc + col] = (bf16_t)v;
        } else {
          ((float*)Cp)[(size_t)z * strideC + (size_t)row * ldc + col] = v;
        }
      }
    }
  }
}

// ---------------- transpose + cast f32[R][C] -> bf16[C][R] ----------------
__global__ __launch_bounds__(256) void tb_transpose_cast(
    const float* __restrict__ in, bf16_t* __restrict__ outT, int R, int C)
{
  __shared__ float tile[32][33];
  int c0 = blockIdx.x * 32;
  int r0 = blockIdx.y * 32;
  int t = threadIdx.x;
  int r = t >> 3;
  int c4 = (t & 7) * 4;
  float4 d = *(const float4*)(in + (size_t)(r0 + r) * C + c0 + c4);
  tile[r][c4 + 0] = d.x; tile[r][c4 + 1] = d.y; tile[r][c4 + 2] = d.z; tile[r][c4 + 3] = d.w;
  __syncthreads();
  int c = t >> 3;
  int r4 = (t & 7) * 4;
  bf16x4 o;
  o[0] = (bf16_t)tile[r4 + 0][c];
  o[1] = (bf16_t)tile[r4 + 1][c];
  o[2] = (bf16_t)tile[r4 + 2][c];
  o[3] = (bf16_t)tile[r4 + 3][c];
  *(bf16x4*)(outT + (size_t)(c0 + c) * R + r0 + r4) = o;
}

// ---------------- transpose bf16 [R][C](ldin) -> bf16 [C][R](ldout), batched ----------------
__global__ __launch_bounds__(256) void tb_transpose_bf16(
    const bf16_t* __restrict__ in, int ldin, long long sIn,
    bf16_t* __restrict__ out, int ldout, long long sOut)
{
  __shared__ bf16_t tile[32][40];
  int z = blockIdx.z;
  const bf16_t* src = in + (size_t)z * sIn;
  bf16_t* dst = out + (size_t)z * sOut;
  int c0 = blockIdx.x * 32;
  int r0 = blockIdx.y * 32;
  int t = threadIdx.x;
  int r = t >> 3;
  int c4 = (t & 7) * 4;
  bf16x4 d = *(const bf16x4*)(src + (size_t)(r0 + r) * ldin + c0 + c4);
  *(bf16x4*)&tile[r][c4] = d;
  __syncthreads();
  int c = t >> 3;
  int r4 = (t & 7) * 4;
  bf16x4 o;
  o[0] = tile[r4 + 0][c];
  o[1] = tile[r4 + 1][c];
  o[2] = tile[r4 + 2][c];
  o[3] = tile[r4 + 3][c];
  *(bf16x4*)(dst + (size_t)(c0 + c) * ldout + r0 + r4) = o;
}

// ---------------- LayerNorm (fp32 in, bf16 out), one block per row of 2048 ----------------
__global__ __launch_bounds__(256) void tb_layernorm(
    const float* __restrict__ x, const float* __restrict__ g, const float* __restrict__ b,
    bf16_t* __restrict__ h)
{
  __shared__ float sa[4], sb[4];
  int row = blockIdx.x;
  int t = threadIdx.x;
  const float* xr = x + (size_t)row * 2048;
  float4 v0 = *(const float4*)(xr + t * 8);
  float4 v1 = *(const float4*)(xr + t * 8 + 4);
  float a[8] = {v0.x, v0.y, v0.z, v0.w, v1.x, v1.y, v1.z, v1.w};
  float s = 0.f, q = 0.f;
#pragma unroll
  for (int j = 0; j < 8; ++j) { s += a[j]; q += a[j] * a[j]; }
#pragma unroll
  for (int o = 32; o; o >>= 1) { s += __shfl_down(s, o); q += __shfl_down(q, o); }
  int w = t >> 6, l = t & 63;
  if (l == 0) { sa[w] = s; sb[w] = q; }
  __syncthreads();
  if (t == 0) {
    sa[0] = sa[0] + sa[1] + sa[2] + sa[3];
    sb[0] = sb[0] + sb[1] + sb[2] + sb[3];
  }
  __syncthreads();
  float mu = sa[0] * (1.0f / 2048.0f);
  float var = sb[0] * (1.0f / 2048.0f) - mu * mu;
  float rs = rsqrtf(var + 1e-5f);
  float4 g0 = *(const float4*)(g + t * 8);
  float4 g1 = *(const float4*)(g + t * 8 + 4);
  float4 b0 = *(const float4*)(b + t * 8);
  float4 b1 = *(const float4*)(b + t * 8 + 4);
  float gv[8] = {g0.x, g0.y, g0.z, g0.w, g1.x, g1.y, g1.z, g1.w};
  float bv[8] = {b0.x, b0.y, b0.z, b0.w, b1.x, b1.y, b1.z, b1.w};
  bf16x8 o8;
#pragma unroll
  for (int j = 0; j < 8; ++j) o8[j] = (bf16_t)((a[j] - mu) * rs * gv[j] + bv[j]);
  *(bf16x8*)(h + (size_t)row * 2048 + t * 8) = o8;
}

// ---------------- Softmax (fp32 in, bf16 out), one block per row of 2048 ----------------
__global__ __launch_bounds__(256) void tb_softmax(
    const float* __restrict__ S, bf16_t* __restrict__ P)
{
  __shared__ float sa[4];
  int row = blockIdx.x;
  int t = threadIdx.x;
  const float* sr = S + (size_t)row * 2048;
  float4 a0 = *(const float4*)(sr + t * 8);
  float4 a1 = *(const float4*)(sr + t * 8 + 4);
  float v[8] = {a0.x, a0.y, a0.z, a0.w, a1.x, a1.y, a1.z, a1.w};
  float m = v[0];
#pragma unroll
  for (int j = 1; j < 8; ++j) m = fmaxf(m, v[j]);
#pragma unroll
  for (int o = 32; o; o >>= 1) m = fmaxf(m, __shfl_down(m, o));
  int w = t >> 6, l = t & 63;
  if (l == 0) sa[w] = m;
  __syncthreads();
  if (t == 0) sa[0] = fmaxf(fmaxf(sa[0], sa[1]), fmaxf(sa[2], sa[3]));
  __syncthreads();
  m = sa[0];
  __syncthreads();
  float s = 0.f;
#pragma unroll
  for (int j = 0; j < 8; ++j) { v[j] = expf(v[j] - m); s += v[j]; }
#pragma unroll
  for (int o = 32; o; o >>= 1) s += __shfl_down(s, o);
  if (l == 0) sa[w] = s;
  __syncthreads();
  if (t == 0) sa[0] = sa[0] + sa[1] + sa[2] + sa[3];
  __syncthreads();
  float inv = 1.0f / sa[0];
  bf16x8 o8;
#pragma unroll
  for (int j = 0; j < 8; ++j) o8[j] = (bf16_t)(v[j] * inv);
  *(bf16x8*)(P + (size_t)row * 2048 + t * 8) = o8;
}

// ---------------- host ----------------
extern "C" void kernel_launch(void* const* d_in, const int* in_sizes, int n_in,
                              void* d_out, int out_size, void* d_ws, size_t ws_size,
                              hipStream_t stream) {
  const float* x     = (const float*)d_in[0];
  const float* ln1_g = (const float*)d_in[1];
  const float* ln1_b = (const float*)d_in[2];
  const float* ln2_g = (const float*)d_in[3];
  const float* ln2_b = (const float*)d_in[4];
  const float* qkv_w = (const float*)d_in[5];
  const float* qkv_b = (const float*)d_in[6];
  const float* out_w = (const float*)d_in[7];
  const float* out_b = (const float*)d_in[8];
  const float* w1    = (const float*)d_in[9];
  const float* b1    = (const float*)d_in[10];
  const float* w2    = (const float*)d_in[11];
  const float* b2    = (const float*)d_in[12];
  float* out = (float*)d_out;
  char* ws = (char*)d_ws;

  // workspace layout (bytes), total 268,435,456
  bf16_t* qkv_wT = (bf16_t*)(ws + 0);           // [6144][2048] bf16 = 25,165,824
  bf16_t* out_wT = (bf16_t*)(ws + 25165824);    // [2048][2048] bf16 =  8,388,608
  bf16_t* w1T    = (bf16_t*)(ws + 33554432);    // [8192][2048] bf16 = 33,554,432
  bf16_t* w2T    = (bf16_t*)(ws + 67108864);    // [2048][8192] bf16 = 33,554,432
  bf16_t* h_bf   = (bf16_t*)(ws + 100663296);   // [4096][2048] bf16 = 16,777,216
  bf16_t* qkv_bf = (bf16_t*)(ws + 117440512);   // [4096][6144] bf16 = 50,331,648
  float*  scores = (float*)(ws + 167772160);    // [2][2048][2048] f32 = 33,554,432
  bf16_t* attn_bf= (bf16_t*)(ws + 201326592);   // [2][2048][2048] bf16 = 16,777,216
  bf16_t* ao_bf  = (bf16_t*)(ws + 218103808);   // [4096][2048] bf16 = 16,777,216
  float*  x2     = (float*)(ws + 234881024);    // [4096][2048] f32 = 33,554,432
  bf16_t* mid_bf = (bf16_t*)(ws + 117440512);   // alias qkv_bf+scores (dead by MLP1)
  bf16_t* Vt     = (bf16_t*)(ws + 234881024);   // [2][2048][2048] bf16, aliases x2 (dead by step 8)

  const float inv_sqrt_h = 0.022097086912079608f; // 1/sqrt(2048)

  // 1) weight transposes (fp32 -> bf16 [N][K])
  tb_transpose_cast<<<dim3(6144 / 32, 2048 / 32), 256, 0, stream>>>(qkv_w, qkv_wT, 2048, 6144);
  tb_transpose_cast<<<dim3(2048 / 32, 2048 / 32), 256, 0, stream>>>(out_w, out_wT, 2048, 2048);
  tb_transpose_cast<<<dim3(8192 / 32, 2048 / 32), 256, 0, stream>>>(w1, w1T, 2048, 8192);
  tb_transpose_cast<<<dim3(2048 / 32, 8192 / 32), 256, 0, stream>>>(w2, w2T, 8192, 2048);

  // 2) LN1: x -> h_bf
  tb_layernorm<<<4096, 256, 0, stream>>>(x, ln1_g, ln1_b, h_bf);

  // 3) QKV: h_bf @ qkv_w + qkv_b -> qkv_bf  (M=4096, N=6144, K=2048)
  tb_gemm8<EPI_BF16_BIAS><<<dim3(24, 16, 1), 512, 0, stream>>>(
      h_bf, 2048, 0, qkv_wT, 2048, 0, qkv_b, nullptr, qkv_bf, 6144, 0, 2048, 1.0f);

  // 4) V transpose: qkv_bf[z][t][4096+h] -> Vt[z][h][t]
  tb_transpose_bf16<<<dim3(64, 64, 2), 256, 0, stream>>>(
      qkv_bf + 4096, 6144, 2048LL * 6144, Vt, 2048, 2048LL * 2048);

  // 5) scores[z] = q[z] @ k[z]^T / sqrt(H)  (M=N=K=2048, z=2)
  tb_gemm8<EPI_F32_SCALE><<<dim3(8, 8, 2), 512, 0, stream>>>(
      qkv_bf, 6144, 2048LL * 6144, qkv_bf + 2048, 6144, 2048LL * 6144,
      nullptr, nullptr, scores, 2048, 2048LL * 2048, 2048, inv_sqrt_h);

  // 6) softmax rows -> attn_bf
  tb_softmax<<<4096, 256, 0, stream>>>(scores, attn_bf);

  // 7) PV: attn[z] @ v[z] -> ao_bf ; B = Vt[z] is [N=h][K=t]
  tb_gemm8<EPI_BF16><<<dim3(8, 8, 2), 512, 0, stream>>>(
      attn_bf, 2048, 2048LL * 2048, Vt, 2048, 2048LL * 2048,
      nullptr, nullptr, ao_bf, 2048, 2048LL * 2048, 2048, 1.0f);

  // 8) out-proj + residual: x2 = x + ao_bf @ out_w + out_b  (M=4096, N=2048, K=2048)
  tb_gemm8<EPI_F32_BIAS_RES><<<dim3(8, 16, 1), 512, 0, stream>>>(
      ao_bf, 2048, 0, out_wT, 2048, 0, out_b, x, x2, 2048, 0, 2048, 1.0f);

  // 9) LN2: x2 -> h_bf (reuse)
  tb_layernorm<<<4096, 256, 0, stream>>>(x2, ln2_g, ln2_b, h_bf);

  // 10) MLP1 + GELU: mid_bf = gelu(h_bf @ w1 + b1)  (M=4096, N=8192, K=2048)
  tb_gemm8<EPI_BF16_BIAS_GELU><<<dim3(32, 16, 1), 512, 0, stream>>>(
      h_bf, 2048, 0, w1T, 2048, 0, b1, nullptr, mid_bf, 8192, 0, 2048, 1.0f);

  // 11) MLP2 + residual: out = x2 + mid_bf @ w2 + b2  (M=4096, N=2048, K=8192)
  tb_gemm8<EPI_F32_BIAS_RES><<<dim3(8, 16, 1), 512, 0, stream>>>(
      mid_bf, 8192, 0, w2T, 8192, 0, b2, x2, out, 2048, 0, 8192, 1.0f);
}

// Round 4
// 745.721 us; speedup vs baseline: 1.3149x; 1.0613x over previous
//
#include <hip/hip_runtime.h>
#include <hip/hip_bf16.h>
#include <math.h>

typedef __bf16 bf16_t;
typedef __bf16 bf16x8 __attribute__((ext_vector_type(8)));
typedef __bf16 bf16x4 __attribute__((ext_vector_type(4)));
typedef float  f32x4  __attribute__((ext_vector_type(4)));

enum { EPI_BF16_BIAS = 0, EPI_F32_SCALE = 1, EPI_BF16 = 2, EPI_F32_BIAS_RES = 3, EPI_BF16_BIAS_GELU = 4 };

__device__ __forceinline__ float gelu_exact(float v) {
  return 0.5f * v * (1.0f + erff(v * 0.7071067811865476f));
}

__device__ __forceinline__ void gld_lds16(const bf16_t* g, bf16_t* l) {
  __builtin_amdgcn_global_load_lds(
      (const __attribute__((address_space(1))) uint32_t*)(uintptr_t)g,
      (__attribute__((address_space(3))) uint32_t*)(uintptr_t)l, 16, 0, 0);
}

#define SB()    __builtin_amdgcn_s_barrier()
#define LGKM0() do { asm volatile("s_waitcnt lgkmcnt(0)" ::: "memory"); __builtin_amdgcn_sched_barrier(0); } while(0)
#define VMW(N)  asm volatile("s_waitcnt vmcnt(" #N ")" ::: "memory")
#define LGKMW(N) asm volatile("s_waitcnt lgkmcnt(" #N ")" ::: "memory")

// swizzled LDS read: 16B frag at (rowbase+lr, k-slot (ks*4+lg) XOR (lr&7))
#define RD(base, rowbase, ks) \
  (*(const bf16x8*)((base) + ((rowbase) + lr) * 64 + (((((ks) << 2) | lg)) ^ (lr & 7)) * 8))

#define DO_MFMA(IBASE, JBASE) \
  __builtin_amdgcn_s_setprio(1); \
  { _Pragma("unroll") for (int ii = 0; ii < 4; ++ii) \
    _Pragma("unroll") for (int jj = 0; jj < 2; ++jj) \
    _Pragma("unroll") for (int ks = 0; ks < 2; ++ks) \
      acc[(IBASE)+ii][(JBASE)+jj] = __builtin_amdgcn_mfma_f32_16x16x32_bf16( \
          aF[ii][ks], bF[jj][ks], acc[(IBASE)+ii][(JBASE)+jj], 0, 0, 0); } \
  __builtin_amdgcn_s_setprio(0);

// ---------------- GEMM: 256x256 tile, BK=64, 8 waves, m201-style 4-phase pipeline ----
// C[M][N] = A[M][K] @ B^T (+ epilogue). A:[M][K] bf16 (lda), B:[N][K] bf16 (ldb).
// M,N multiples of 256; K multiple of 64 (NT >= 2).
// Phase = { ds_reads(this quadrant) ; stage one half-tile(t+1) ; counted vmcnt ;
//           barrier ; lgkmcnt(0) ; setprio(1) 16xMFMA setprio(0) ; barrier }
template<int EPI>
__global__ __launch_bounds__(512, 2) void tb_gemm8(
    const bf16_t* __restrict__ A, int lda, long long strideA,
    const bf16_t* __restrict__ B, int ldb, long long strideB,
    const float* __restrict__ bias,
    const float* __restrict__ resid,
    void* __restrict__ Cp, int ldc, long long strideC,
    int K, float scale)
{
  __shared__ __align__(16) bf16_t sm[65536];  // 128 KiB: 2 bufs x (A 16384 + B 16384 elems)

  const int tid = threadIdx.x;
  const int lane = tid & 63;
  const int wid = tid >> 6;
  const int wm = wid >> 2;   // 0..1  (M wave group, 16-row interleave)
  const int wn = wid & 3;    // 0..3  (N wave group, 16-col interleave)
  const int lr = lane & 15;
  const int lg = lane >> 4;
  const int z = blockIdx.z;
  const int m0 = blockIdx.y * 256;
  const int n0 = blockIdx.x * 256;

  const bf16_t* Ag = A + (size_t)z * strideA + (size_t)m0 * lda;
  const bf16_t* Bg = B + (size_t)z * strideB + (size_t)n0 * ldb;

  const int l3 = lane >> 3;                 // row-within-chunk
  const int sl8 = ((lane & 7) ^ l3) << 3;   // inverse-swizzled source col (elems)

  f32x4 acc[8][4];
#pragma unroll
  for (int i = 0; i < 8; ++i)
#pragma unroll
    for (int j = 0; j < 4; ++j) acc[i][j] = (f32x4){0.f, 0.f, 0.f, 0.f};

  // stage one half-tile (128 rows) of one matrix: 2 gload_lds per wave.
  // LDS dest linear; global source column pre-permuted with the read swizzle.
  auto stageM = [&](const bf16_t* G, int ld, bf16_t* dst, int kt, int H) {
#pragma unroll
    for (int q = 0; q < 2; ++q) {
      int c = (wid << 1) + q;                 // chunk 0..15
      int row = (H << 7) + (c << 3) + l3;
      gld_lds16(G + (size_t)row * ld + kt + sl8, dst + (H << 13) + (c << 9) + lane * 8);
    }
  };

  const int NT = K >> 6;
  // prologue: tile 0 halves in order [A-h0, B-h0, B-h1, A-h1] -> 8 loads in flight
  stageM(Ag, lda, sm, 0, 0);
  stageM(Bg, ldb, sm + 16384, 0, 0);
  stageM(Bg, ldb, sm + 16384, 0, 1);
  stageM(Ag, lda, sm, 0, 1);
  VMW(4);   // A-h0(0), B-h0(0) landed
  SB();

  bf16x8 aF[4][2], bF[2][2];

  for (int t = 0; t < NT; ++t) {
    bf16_t* cura = sm + ((t & 1) << 15);
    bf16_t* curb = cura + 16384;
    bf16_t* nxta = sm + (((t + 1) & 1) << 15);
    bf16_t* nxtb = nxta + 16384;
    const int ktn = (t + 1) << 6;
    const bool last = (t == NT - 1);

    // ---- phase 0: quadrant (m-h0, n-h0) ----
#pragma unroll
    for (int ii = 0; ii < 4; ++ii) {
      aF[ii][0] = RD(cura, ii * 32 + wm * 16, 0);
      aF[ii][1] = RD(cura, ii * 32 + wm * 16, 1);
    }
#pragma unroll
    for (int jj = 0; jj < 2; ++jj) {
      bF[jj][0] = RD(curb, jj * 64 + wn * 16, 0);
      bF[jj][1] = RD(curb, jj * 64 + wn * 16, 1);
    }
    if (!last) stageM(Ag, lda, nxta, ktn, 0);       // stage A-h0(t+1)
    if (last) { VMW(2); } else { VMW(4); }          // confirm B-h1(t)
    LGKMW(8);
    SB();
    LGKM0();
    DO_MFMA(0, 0);
    SB();

    // ---- phase 1: quadrant (m-h0, n-h1) ----
#pragma unroll
    for (int jj = 0; jj < 2; ++jj) {
      bF[jj][0] = RD(curb, 128 + jj * 64 + wn * 16, 0);
      bF[jj][1] = RD(curb, 128 + jj * 64 + wn * 16, 1);
    }
    if (!last) stageM(Bg, ldb, nxtb, ktn, 0);       // stage B-h0(t+1)
    if (last) { VMW(0); } else { VMW(4); }          // confirm A-h1(t)
    SB();
    LGKM0();
    DO_MFMA(0, 2);
    SB();

    // ---- phase 2: quadrant (m-h1, n-h1) ----
#pragma unroll
    for (int ii = 0; ii < 4; ++ii) {
      aF[ii][0] = RD(cura, 128 + ii * 32 + wm * 16, 0);
      aF[ii][1] = RD(cura, 128 + ii * 32 + wm * 16, 1);
    }
    if (!last) stageM(Bg, ldb, nxtb, ktn, 1);       // stage B-h1(t+1)
    SB();
    LGKM0();
    DO_MFMA(4, 2);
    SB();

    // ---- phase 3: quadrant (m-h1, n-h0) ----
#pragma unroll
    for (int jj = 0; jj < 2; ++jj) {
      bF[jj][0] = RD(curb, jj * 64 + wn * 16, 0);
      bF[jj][1] = RD(curb, jj * 64 + wn * 16, 1);
    }
    if (!last) {
      stageM(Ag, lda, nxta, ktn, 1);                // stage A-h1(t+1)
      VMW(4);                                       // confirm A-h0(t+1), B-h0(t+1)
    }
    SB();
    LGKM0();
    DO_MFMA(4, 0);
    SB();
  }

  // ---- epilogue ----
#pragma unroll
  for (int i = 0; i < 8; ++i) {
    const int mr = ((i >> 2) << 7) + ((i & 3) << 5) + (wm << 4);
#pragma unroll
    for (int j = 0; j < 4; ++j) {
      const int nc = ((j >> 1) << 7) + ((j & 1) << 6) + (wn << 4);
#pragma unroll
      for (int r = 0; r < 4; ++r) {
        int row = m0 + mr + lg * 4 + r;
        int col = n0 + nc + lr;
        float v = acc[i][j][r] * scale;
        if constexpr (EPI == EPI_BF16_BIAS || EPI == EPI_F32_BIAS_RES || EPI == EPI_BF16_BIAS_GELU)
          v += bias[col];
        if constexpr (EPI == EPI_BF16_BIAS_GELU)
          v = gelu_exact(v);
        if constexpr (EPI == EPI_F32_BIAS_RES)
          v += resid[(size_t)row * ldc + col];
        if constexpr (EPI == EPI_BF16_BIAS || EPI == EPI_BF16 || EPI == EPI_BF16_BIAS_GELU) {
          ((bf16_t*)Cp)[(size_t)z * strideC + (size_t)row * ldc + col] = (bf16_t)v;
        } else {
          ((float*)Cp)[(size_t)z * strideC + (size_t)row * ldc + col] = v;
        }
      }
    }
  }
}

// ---------------- combine: out = x2 + p0 + p1 + bias (f32, H=2048 cols) ----------------
__global__ __launch_bounds__(256) void tb_combine(
    const float* __restrict__ x2, const float* __restrict__ p0,
    const float* __restrict__ p1, const float* __restrict__ bias,
    float* __restrict__ out)
{
  size_t o = ((size_t)blockIdx.x * 256 + threadIdx.x) * 4;
  float4 a = *(const float4*)(x2 + o);
  float4 b = *(const float4*)(p0 + o);
  float4 c = *(const float4*)(p1 + o);
  float4 bb = *(const float4*)(bias + (o & 2047));
  float4 r;
  r.x = a.x + b.x + c.x + bb.x;
  r.y = a.y + b.y + c.y + bb.y;
  r.z = a.z + b.z + c.z + bb.z;
  r.w = a.w + b.w + c.w + bb.w;
  *(float4*)(out + o) = r;
}

// ---------------- transpose + cast f32[R][C] -> bf16[C][R] ----------------
__global__ __launch_bounds__(256) void tb_transpose_cast(
    const float* __restrict__ in, bf16_t* __restrict__ outT, int R, int C)
{
  __shared__ float tile[32][33];
  int c0 = blockIdx.x * 32;
  int r0 = blockIdx.y * 32;
  int t = threadIdx.x;
  int r = t >> 3;
  int c4 = (t & 7) * 4;
  float4 d = *(const float4*)(in + (size_t)(r0 + r) * C + c0 + c4);
  tile[r][c4 + 0] = d.x; tile[r][c4 + 1] = d.y; tile[r][c4 + 2] = d.z; tile[r][c4 + 3] = d.w;
  __syncthreads();
  int c = t >> 3;
  int r4 = (t & 7) * 4;
  bf16x4 o;
  o[0] = (bf16_t)tile[r4 + 0][c];
  o[1] = (bf16_t)tile[r4 + 1][c];
  o[2] = (bf16_t)tile[r4 + 2][c];
  o[3] = (bf16_t)tile[r4 + 3][c];
  *(bf16x4*)(outT + (size_t)(c0 + c) * R + r0 + r4) = o;
}

// ---------------- transpose bf16 [R][C](ldin) -> bf16 [C][R](ldout), batched ----------------
__global__ __launch_bounds__(256) void tb_transpose_bf16(
    const bf16_t* __restrict__ in, int ldin, long long sIn,
    bf16_t* __restrict__ out, int ldout, long long sOut)
{
  __shared__ bf16_t tile[32][40];
  int z = blockIdx.z;
  const bf16_t* src = in + (size_t)z * sIn;
  bf16_t* dst = out + (size_t)z * sOut;
  int c0 = blockIdx.x * 32;
  int r0 = blockIdx.y * 32;
  int t = threadIdx.x;
  int r = t >> 3;
  int c4 = (t & 7) * 4;
  bf16x4 d = *(const bf16x4*)(src + (size_t)(r0 + r) * ldin + c0 + c4);
  *(bf16x4*)&tile[r][c4] = d;
  __syncthreads();
  int c = t >> 3;
  int r4 = (t & 7) * 4;
  bf16x4 o;
  o[0] = tile[r4 + 0][c];
  o[1] = tile[r4 + 1][c];
  o[2] = tile[r4 + 2][c];
  o[3] = tile[r4 + 3][c];
  *(bf16x4*)(dst + (size_t)(c0 + c) * ldout + r0 + r4) = o;
}

// ---------------- LayerNorm (fp32 in, bf16 out), one block per row of 2048 ----------------
__global__ __launch_bounds__(256) void tb_layernorm(
    const float* __restrict__ x, const float* __restrict__ g, const float* __restrict__ b,
    bf16_t* __restrict__ h)
{
  __shared__ float sa[4], sb[4];
  int row = blockIdx.x;
  int t = threadIdx.x;
  const float* xr = x + (size_t)row * 2048;
  float4 v0 = *(const float4*)(xr + t * 8);
  float4 v1 = *(const float4*)(xr + t * 8 + 4);
  float a[8] = {v0.x, v0.y, v0.z, v0.w, v1.x, v1.y, v1.z, v1.w};
  float s = 0.f, q = 0.f;
#pragma unroll
  for (int j = 0; j < 8; ++j) { s += a[j]; q += a[j] * a[j]; }
#pragma unroll
  for (int o = 32; o; o >>= 1) { s += __shfl_down(s, o); q += __shfl_down(q, o); }
  int w = t >> 6, l = t & 63;
  if (l == 0) { sa[w] = s; sb[w] = q; }
  __syncthreads();
  if (t == 0) {
    sa[0] = sa[0] + sa[1] + sa[2] + sa[3];
    sb[0] = sb[0] + sb[1] + sb[2] + sb[3];
  }
  __syncthreads();
  float mu = sa[0] * (1.0f / 2048.0f);
  float var = sb[0] * (1.0f / 2048.0f) - mu * mu;
  float rs = rsqrtf(var + 1e-5f);
  float4 g0 = *(const float4*)(g + t * 8);
  float4 g1 = *(const float4*)(g + t * 8 + 4);
  float4 b0 = *(const float4*)(b + t * 8);
  float4 b1 = *(const float4*)(b + t * 8 + 4);
  float gv[8] = {g0.x, g0.y, g0.z, g0.w, g1.x, g1.y, g1.z, g1.w};
  float bv[8] = {b0.x, b0.y, b0.z, b0.w, b1.x, b1.y, b1.z, b1.w};
  bf16x8 o8;
#pragma unroll
  for (int j = 0; j < 8; ++j) o8[j] = (bf16_t)((a[j] - mu) * rs * gv[j] + bv[j]);
  *(bf16x8*)(h + (size_t)row * 2048 + t * 8) = o8;
}

// ---------------- Softmax (fp32 in, bf16 out), one block per row of 2048 ----------------
__global__ __launch_bounds__(256) void tb_softmax(
    const float* __restrict__ S, bf16_t* __restrict__ P)
{
  __shared__ float sa[4];
  int row = blockIdx.x;
  int t = threadIdx.x;
  const float* sr = S + (size_t)row * 2048;
  float4 a0 = *(const float4*)(sr + t * 8);
  float4 a1 = *(const float4*)(sr + t * 8 + 4);
  float v[8] = {a0.x, a0.y, a0.z, a0.w, a1.x, a1.y, a1.z, a1.w};
  float m = v[0];
#pragma unroll
  for (int j = 1; j < 8; ++j) m = fmaxf(m, v[j]);
#pragma unroll
  for (int o = 32; o; o >>= 1) m = fmaxf(m, __shfl_down(m, o));
  int w = t >> 6, l = t & 63;
  if (l == 0) sa[w] = m;
  __syncthreads();
  if (t == 0) sa[0] = fmaxf(fmaxf(sa[0], sa[1]), fmaxf(sa[2], sa[3]));
  __syncthreads();
  m = sa[0];
  __syncthreads();
  float s = 0.f;
#pragma unroll
  for (int j = 0; j < 8; ++j) { v[j] = expf(v[j] - m); s += v[j]; }
#pragma unroll
  for (int o = 32; o; o >>= 1) s += __shfl_down(s, o);
  if (l == 0) sa[w] = s;
  __syncthreads();
  if (t == 0) sa[0] = sa[0] + sa[1] + sa[2] + sa[3];
  __syncthreads();
  float inv = 1.0f / sa[0];
  bf16x8 o8;
#pragma unroll
  for (int j = 0; j < 8; ++j) o8[j] = (bf16_t)(v[j] * inv);
  *(bf16x8*)(P + (size_t)row * 2048 + t * 8) = o8;
}

// ---------------- host ----------------
extern "C" void kernel_launch(void* const* d_in, const int* in_sizes, int n_in,
                              void* d_out, int out_size, void* d_ws, size_t ws_size,
                              hipStream_t stream) {
  const float* x     = (const float*)d_in[0];
  const float* ln1_g = (const float*)d_in[1];
  const float* ln1_b = (const float*)d_in[2];
  const float* ln2_g = (const float*)d_in[3];
  const float* ln2_b = (const float*)d_in[4];
  const float* qkv_w = (const float*)d_in[5];
  const float* qkv_b = (const float*)d_in[6];
  const float* out_w = (const float*)d_in[7];
  const float* out_b = (const float*)d_in[8];
  const float* w1    = (const float*)d_in[9];
  const float* b1    = (const float*)d_in[10];
  const float* w2    = (const float*)d_in[11];
  const float* b2    = (const float*)d_in[12];
  float* out = (float*)d_out;
  char* ws = (char*)d_ws;

  // workspace layout (bytes), total 268,435,456
  bf16_t* qkv_wT = (bf16_t*)(ws + 0);           // [6144][2048] bf16 = 25,165,824
  bf16_t* out_wT = (bf16_t*)(ws + 25165824);    // [2048][2048] bf16 =  8,388,608
  bf16_t* w1T    = (bf16_t*)(ws + 33554432);    // [8192][2048] bf16 = 33,554,432
  bf16_t* w2T    = (bf16_t*)(ws + 67108864);    // [2048][8192] bf16 = 33,554,432
  bf16_t* h_bf   = (bf16_t*)(ws + 100663296);   // [4096][2048] bf16 = 16,777,216
  bf16_t* qkv_bf = (bf16_t*)(ws + 117440512);   // [4096][6144] bf16 = 50,331,648
  float*  scores = (float*)(ws + 167772160);    // [2][2048][2048] f32 = 33,554,432
  bf16_t* attn_bf= (bf16_t*)(ws + 201326592);   // [2][2048][2048] bf16 = 16,777,216
  bf16_t* ao_bf  = (bf16_t*)(ws + 218103808);   // [4096][2048] bf16 = 16,777,216
  float*  x2     = (float*)(ws + 234881024);    // [4096][2048] f32 = 33,554,432
  bf16_t* mid_bf = (bf16_t*)(ws + 117440512);   // alias qkv_bf+scores (dead by MLP1)
  bf16_t* Vt     = (bf16_t*)(ws + 234881024);   // aliases x2 (dead by step 8)
  float*  part0  = (float*)(ws + 0);            // [4096][2048] f32, aliases qkv_wT+out_wT (dead by MLP2)
  float*  part1  = (float*)(ws + 201326592);    // [4096][2048] f32, aliases attn_bf+ao_bf (dead by MLP2)

  const float inv_sqrt_h = 0.022097086912079608f; // 1/sqrt(2048)

  // 1) weight transposes (fp32 -> bf16 [N][K])
  tb_transpose_cast<<<dim3(6144 / 32, 2048 / 32), 256, 0, stream>>>(qkv_w, qkv_wT, 2048, 6144);
  tb_transpose_cast<<<dim3(2048 / 32, 2048 / 32), 256, 0, stream>>>(out_w, out_wT, 2048, 2048);
  tb_transpose_cast<<<dim3(8192 / 32, 2048 / 32), 256, 0, stream>>>(w1, w1T, 2048, 8192);
  tb_transpose_cast<<<dim3(2048 / 32, 8192 / 32), 256, 0, stream>>>(w2, w2T, 8192, 2048);

  // 2) LN1: x -> h_bf
  tb_layernorm<<<4096, 256, 0, stream>>>(x, ln1_g, ln1_b, h_bf);

  // 3) QKV: h_bf @ qkv_w + qkv_b -> qkv_bf  (M=4096, N=6144, K=2048)
  tb_gemm8<EPI_BF16_BIAS><<<dim3(24, 16, 1), 512, 0, stream>>>(
      h_bf, 2048, 0, qkv_wT, 2048, 0, qkv_b, nullptr, qkv_bf, 6144, 0, 2048, 1.0f);

  // 4) V transpose: qkv_bf[z][t][4096+h] -> Vt[z][h][t]
  tb_transpose_bf16<<<dim3(64, 64, 2), 256, 0, stream>>>(
      qkv_bf + 4096, 6144, 2048LL * 6144, Vt, 2048, 2048LL * 2048);

  // 5) scores[z] = q[z] @ k[z]^T / sqrt(H)  (M=N=K=2048, z=2)
  tb_gemm8<EPI_F32_SCALE><<<dim3(8, 8, 2), 512, 0, stream>>>(
      qkv_bf, 6144, 2048LL * 6144, qkv_bf + 2048, 6144, 2048LL * 6144,
      nullptr, nullptr, scores, 2048, 2048LL * 2048, 2048, inv_sqrt_h);

  // 6) softmax rows -> attn_bf
  tb_softmax<<<4096, 256, 0, stream>>>(scores, attn_bf);

  // 7) PV: attn[z] @ v[z] -> ao_bf ; B = Vt[z] is [N=h][K=t]
  tb_gemm8<EPI_BF16><<<dim3(8, 8, 2), 512, 0, stream>>>(
      attn_bf, 2048, 2048LL * 2048, Vt, 2048, 2048LL * 2048,
      nullptr, nullptr, ao_bf, 2048, 2048LL * 2048, 2048, 1.0f);

  // 8) out-proj + residual: x2 = x + ao_bf @ out_w + out_b  (M=4096, N=2048, K=2048)
  tb_gemm8<EPI_F32_BIAS_RES><<<dim3(8, 16, 1), 512, 0, stream>>>(
      ao_bf, 2048, 0, out_wT, 2048, 0, out_b, x, x2, 2048, 0, 2048, 1.0f);

  // 9) LN2: x2 -> h_bf (reuse)
  tb_layernorm<<<4096, 256, 0, stream>>>(x2, ln2_g, ln2_b, h_bf);

  // 10) MLP1 + GELU: mid_bf = gelu(h_bf @ w1 + b1)  (M=4096, N=8192, K=2048)
  tb_gemm8<EPI_BF16_BIAS_GELU><<<dim3(32, 16, 1), 512, 0, stream>>>(
      h_bf, 2048, 0, w1T, 2048, 0, b1, nullptr, mid_bf, 8192, 0, 2048, 1.0f);

  // 11) MLP2 split-K x2: part_z = mid_bf[:, z*4096:] @ w2T[:, z*4096:]^T  (256 blocks)
  //     z offsets A and B by 4096 columns (elements) via strideA/strideB.
  tb_gemm8<EPI_F32_SCALE><<<dim3(8, 16, 2), 512, 0, stream>>>(
      mid_bf, 8192, 4096, w2T, 8192, 4096,
      nullptr, nullptr, part0, 2048, 50331648LL, 4096, 1.0f);

  // 12) combine: out = x2 + part0 + part1 + b2
  tb_combine<<<8192, 256, 0, stream>>>(x2, part0, part1, b2, out);
}

// Round 5
// 734.463 us; speedup vs baseline: 1.3350x; 1.0153x over previous
//
#include <hip/hip_runtime.h>
#include <hip/hip_bf16.h>
#include <math.h>

typedef __bf16 bf16_t;
typedef __bf16 bf16x8 __attribute__((ext_vector_type(8)));
typedef __bf16 bf16x4 __attribute__((ext_vector_type(4)));
typedef float  f32x4  __attribute__((ext_vector_type(4)));

enum { EPI_BF16_BIAS = 0, EPI_F32_SCALE = 1, EPI_BF16 = 2, EPI_F32_BIAS_RES = 3, EPI_BF16_BIAS_GELU = 4 };

__device__ __forceinline__ float gelu_exact(float v) {
  return 0.5f * v * (1.0f + erff(v * 0.7071067811865476f));
}

__device__ __forceinline__ void gld_lds16(const bf16_t* g, bf16_t* l) {
  __builtin_amdgcn_global_load_lds(
      (const __attribute__((address_space(1))) uint32_t*)(uintptr_t)g,
      (__attribute__((address_space(3))) uint32_t*)(uintptr_t)l, 16, 0, 0);
}

#define SB()    __builtin_amdgcn_s_barrier()
#define SCHED() __builtin_amdgcn_sched_barrier(0)
#define VMW0()  asm volatile("s_waitcnt vmcnt(0)" ::: "memory")

// swizzled LDS read: 16B frag at (rowbase+lr, k-slot (ks*4+lg) XOR (lr&7))
#define RD(base, rowbase, ks) \
  (*(const bf16x8*)((base) + ((rowbase) + lr) * 64 + (((((ks) << 2) | lg)) ^ (lr & 7)) * 8))

// ---------------- GEMM: 256x256 tile, BK=64, 8 waves, 1-barrier counted-vmcnt K-loop ----
// C[M][N] = A[M][K] @ B^T (+ epilogue). A:[M][K] bf16 (lda), B:[N][K] bf16 (ldb).
// M,N multiples of 256; K multiple of 64.
// K-tile body: { fence; stage(t+1) 8x gload_lds; 24x ds_read_b128; 64 MFMA
//                (compiler-interleaved, counted lgkm); fence; vmcnt(0); s_barrier }
template<int EPI>
__global__ __launch_bounds__(512, 2) void tb_gemm8(
    const bf16_t* __restrict__ A, int lda, long long strideA,
    const bf16_t* __restrict__ B, int ldb, long long strideB,
    const float* __restrict__ bias,
    const float* __restrict__ resid,
    void* __restrict__ Cp, int ldc, long long strideC,
    int K, float scale)
{
  __shared__ __align__(16) bf16_t sm[65536];  // 128 KiB: 2 bufs x (A 16384 + B 16384 elems)

  const int tid = threadIdx.x;
  const int lane = tid & 63;
  const int wid = tid >> 6;
  const int wm = wid >> 2;   // 0..1  (M wave group, 16-row interleave)
  const int wn = wid & 3;    // 0..3  (N wave group, 16-col interleave)
  const int lr = lane & 15;
  const int lg = lane >> 4;
  const int z = blockIdx.z;
  const int m0 = blockIdx.y * 256;
  const int n0 = blockIdx.x * 256;

  const bf16_t* Ag = A + (size_t)z * strideA + (size_t)m0 * lda;
  const bf16_t* Bg = B + (size_t)z * strideB + (size_t)n0 * ldb;

  const int l3 = lane >> 3;                 // row-within-chunk
  const int sl8 = ((lane & 7) ^ l3) << 3;   // inverse-swizzled source col (elems)

  f32x4 acc[8][4];
#pragma unroll
  for (int i = 0; i < 8; ++i)
#pragma unroll
    for (int j = 0; j < 4; ++j) acc[i][j] = (f32x4){0.f, 0.f, 0.f, 0.f};

  // stage full K-tile kt (A + B, 4 half-tiles) into buffer parity par: 8 gload_lds/wave.
  // All row*ld products are t-loop-invariant -> LICM keeps them in registers.
  auto stage = [&](int par, int kt) {
    bf16_t* da = sm + (par << 15);
    bf16_t* db = da + 16384;
#pragma unroll
    for (int h = 0; h < 2; ++h)
#pragma unroll
      for (int q = 0; q < 2; ++q) {
        int c = (wid << 1) + q;                 // chunk 0..15
        int row = (h << 7) + (c << 3) + l3;
        gld_lds16(Ag + (size_t)row * lda + kt + sl8, da + (h << 13) + (c << 9) + lane * 8);
        gld_lds16(Bg + (size_t)row * ldb + kt + sl8, db + (h << 13) + (c << 9) + lane * 8);
      }
  };

  const int NT = K >> 6;
  stage(0, 0);
  VMW0();
  SB();

  for (int t = 0; t < NT; ++t) {
    SCHED();
    const bf16_t* cura = sm + ((t & 1) << 15);
    const bf16_t* curb = cura + 16384;
    if (t + 1 < NT) stage((t + 1) & 1, (t + 1) << 6);

    bf16x8 bF[4][2], aF[4][2];
#pragma unroll
    for (int jj = 0; jj < 4; ++jj) {
      bF[jj][0] = RD(curb, jj * 64 + wn * 16, 0);
      bF[jj][1] = RD(curb, jj * 64 + wn * 16, 1);
    }
#pragma unroll
    for (int ii = 0; ii < 4; ++ii) {
      aF[ii][0] = RD(cura, ii * 32 + wm * 16, 0);
      aF[ii][1] = RD(cura, ii * 32 + wm * 16, 1);
    }
    __builtin_amdgcn_s_setprio(1);
#pragma unroll
    for (int ii = 0; ii < 4; ++ii)
#pragma unroll
      for (int jj = 0; jj < 4; ++jj)
#pragma unroll
        for (int ks = 0; ks < 2; ++ks)
          acc[ii][jj] = __builtin_amdgcn_mfma_f32_16x16x32_bf16(aF[ii][ks], bF[jj][ks], acc[ii][jj], 0, 0, 0);
    __builtin_amdgcn_s_setprio(0);
#pragma unroll
    for (int ii = 0; ii < 4; ++ii) {
      aF[ii][0] = RD(cura, 128 + ii * 32 + wm * 16, 0);
      aF[ii][1] = RD(cura, 128 + ii * 32 + wm * 16, 1);
    }
    __builtin_amdgcn_s_setprio(1);
#pragma unroll
    for (int ii = 0; ii < 4; ++ii)
#pragma unroll
      for (int jj = 0; jj < 4; ++jj)
#pragma unroll
        for (int ks = 0; ks < 2; ++ks)
          acc[4 + ii][jj] = __builtin_amdgcn_mfma_f32_16x16x32_bf16(aF[ii][ks], bF[jj][ks], acc[4 + ii][jj], 0, 0, 0);
    __builtin_amdgcn_s_setprio(0);

    SCHED();                        // keep all tile-t ops (and their waits) above the barrier
    if (t + 1 < NT) {
      VMW0();                       // t+1 loads issued a full tile ago -> ~no stall
      SB();
    }
  }

  // ---- epilogue ----
#pragma unroll
  for (int i = 0; i < 8; ++i) {
    const int mr = ((i >> 2) << 7) + ((i & 3) << 5) + (wm << 4);
#pragma unroll
    for (int j = 0; j < 4; ++j) {
      const int nc = j * 64 + (wn << 4);
#pragma unroll
      for (int r = 0; r < 4; ++r) {
        int row = m0 + mr + lg * 4 + r;
        int col = n0 + nc + lr;
        float v = acc[i][j][r] * scale;
        if constexpr (EPI == EPI_BF16_BIAS || EPI == EPI_F32_BIAS_RES || EPI == EPI_BF16_BIAS_GELU)
          v += bias[col];
        if constexpr (EPI == EPI_BF16_BIAS_GELU)
          v = gelu_exact(v);
        if constexpr (EPI == EPI_F32_BIAS_RES)
          v += resid[(size_t)row * ldc + col];
        if constexpr (EPI == EPI_BF16_BIAS || EPI == EPI_BF16 || EPI == EPI_BF16_BIAS_GELU) {
          ((bf16_t*)Cp)[(size_t)z * strideC + (size_t)row * ldc + col] = (bf16_t)v;
        } else {
          ((float*)Cp)[(size_t)z * strideC + (size_t)row * ldc + col] = v;
        }
      }
    }
  }
}

// ---------------- combine: out = x2 + p0 + p1 + bias (f32, H=2048 cols) ----------------
__global__ __launch_bounds__(256) void tb_combine(
    const float* __restrict__ x2, const float* __restrict__ p0,
    const float* __restrict__ p1, const float* __restrict__ bias,
    float* __restrict__ out)
{
  size_t o = ((size_t)blockIdx.x * 256 + threadIdx.x) * 4;
  float4 a = *(const float4*)(x2 + o);
  float4 b = *(const float4*)(p0 + o);
  float4 c = *(const float4*)(p1 + o);
  float4 bb = *(const float4*)(bias + (o & 2047));
  float4 r;
  r.x = a.x + b.x + c.x + bb.x;
  r.y = a.y + b.y + c.y + bb.y;
  r.z = a.z + b.z + c.z + bb.z;
  r.w = a.w + b.w + c.w + bb.w;
  *(float4*)(out + o) = r;
}

// ---------------- transpose + cast f32[R][C] -> bf16[C][R] ----------------
__global__ __launch_bounds__(256) void tb_transpose_cast(
    const float* __restrict__ in, bf16_t* __restrict__ outT, int R, int C)
{
  __shared__ float tile[32][33];
  int c0 = blockIdx.x * 32;
  int r0 = blockIdx.y * 32;
  int t = threadIdx.x;
  int r = t >> 3;
  int c4 = (t & 7) * 4;
  float4 d = *(const float4*)(in + (size_t)(r0 + r) * C + c0 + c4);
  tile[r][c4 + 0] = d.x; tile[r][c4 + 1] = d.y; tile[r][c4 + 2] = d.z; tile[r][c4 + 3] = d.w;
  __syncthreads();
  int c = t >> 3;
  int r4 = (t & 7) * 4;
  bf16x4 o;
  o[0] = (bf16_t)tile[r4 + 0][c];
  o[1] = (bf16_t)tile[r4 + 1][c];
  o[2] = (bf16_t)tile[r4 + 2][c];
  o[3] = (bf16_t)tile[r4 + 3][c];
  *(bf16x4*)(outT + (size_t)(c0 + c) * R + r0 + r4) = o;
}

// ---------------- transpose bf16 [R][C](ldin) -> bf16 [C][R](ldout), batched ----------------
__global__ __launch_bounds__(256) void tb_transpose_bf16(
    const bf16_t* __restrict__ in, int ldin, long long sIn,
    bf16_t* __restrict__ out, int ldout, long long sOut)
{
  __shared__ bf16_t tile[32][40];
  int z = blockIdx.z;
  const bf16_t* src = in + (size_t)z * sIn;
  bf16_t* dst = out + (size_t)z * sOut;
  int c0 = blockIdx.x * 32;
  int r0 = blockIdx.y * 32;
  int t = threadIdx.x;
  int r = t >> 3;
  int c4 = (t & 7) * 4;
  bf16x4 d = *(const bf16x4*)(src + (size_t)(r0 + r) * ldin + c0 + c4);
  *(bf16x4*)&tile[r][c4] = d;
  __syncthreads();
  int c = t >> 3;
  int r4 = (t & 7) * 4;
  bf16x4 o;
  o[0] = tile[r4 + 0][c];
  o[1] = tile[r4 + 1][c];
  o[2] = tile[r4 + 2][c];
  o[3] = tile[r4 + 3][c];
  *(bf16x4*)(dst + (size_t)(c0 + c) * ldout + r0 + r4) = o;
}

// ---------------- LayerNorm (fp32 in, bf16 out), one block per row of 2048 ----------------
__global__ __launch_bounds__(256) void tb_layernorm(
    const float* __restrict__ x, const float* __restrict__ g, const float* __restrict__ b,
    bf16_t* __restrict__ h)
{
  __shared__ float sa[4], sb[4];
  int row = blockIdx.x;
  int t = threadIdx.x;
  const float* xr = x + (size_t)row * 2048;
  float4 v0 = *(const float4*)(xr + t * 8);
  float4 v1 = *(const float4*)(xr + t * 8 + 4);
  float a[8] = {v0.x, v0.y, v0.z, v0.w, v1.x, v1.y, v1.z, v1.w};
  float s = 0.f, q = 0.f;
#pragma unroll
  for (int j = 0; j < 8; ++j) { s += a[j]; q += a[j] * a[j]; }
#pragma unroll
  for (int o = 32; o; o >>= 1) { s += __shfl_down(s, o); q += __shfl_down(q, o); }
  int w = t >> 6, l = t & 63;
  if (l == 0) { sa[w] = s; sb[w] = q; }
  __syncthreads();
  if (t == 0) {
    sa[0] = sa[0] + sa[1] + sa[2] + sa[3];
    sb[0] = sb[0] + sb[1] + sb[2] + sb[3];
  }
  __syncthreads();
  float mu = sa[0] * (1.0f / 2048.0f);
  float var = sb[0] * (1.0f / 2048.0f) - mu * mu;
  float rs = rsqrtf(var + 1e-5f);
  float4 g0 = *(const float4*)(g + t * 8);
  float4 g1 = *(const float4*)(g + t * 8 + 4);
  float4 b0 = *(const float4*)(b + t * 8);
  float4 b1 = *(const float4*)(b + t * 8 + 4);
  float gv[8] = {g0.x, g0.y, g0.z, g0.w, g1.x, g1.y, g1.z, g1.w};
  float bv[8] = {b0.x, b0.y, b0.z, b0.w, b1.x, b1.y, b1.z, b1.w};
  bf16x8 o8;
#pragma unroll
  for (int j = 0; j < 8; ++j) o8[j] = (bf16_t)((a[j] - mu) * rs * gv[j] + bv[j]);
  *(bf16x8*)(h + (size_t)row * 2048 + t * 8) = o8;
}

// ---------------- Softmax (fp32 in, bf16 out), one block per row of 2048 ----------------
__global__ __launch_bounds__(256) void tb_softmax(
    const float* __restrict__ S, bf16_t* __restrict__ P)
{
  __shared__ float sa[4];
  int row = blockIdx.x;
  int t = threadIdx.x;
  const float* sr = S + (size_t)row * 2048;
  float4 a0 = *(const float4*)(sr + t * 8);
  float4 a1 = *(const float4*)(sr + t * 8 + 4);
  float v[8] = {a0.x, a0.y, a0.z, a0.w, a1.x, a1.y, a1.z, a1.w};
  float m = v[0];
#pragma unroll
  for (int j = 1; j < 8; ++j) m = fmaxf(m, v[j]);
#pragma unroll
  for (int o = 32; o; o >>= 1) m = fmaxf(m, __shfl_down(m, o));
  int w = t >> 6, l = t & 63;
  if (l == 0) sa[w] = m;
  __syncthreads();
  if (t == 0) sa[0] = fmaxf(fmaxf(sa[0], sa[1]), fmaxf(sa[2], sa[3]));
  __syncthreads();
  m = sa[0];
  __syncthreads();
  float s = 0.f;
#pragma unroll
  for (int j = 0; j < 8; ++j) { v[j] = expf(v[j] - m); s += v[j]; }
#pragma unroll
  for (int o = 32; o; o >>= 1) s += __shfl_down(s, o);
  if (l == 0) sa[w] = s;
  __syncthreads();
  if (t == 0) sa[0] = sa[0] + sa[1] + sa[2] + sa[3];
  __syncthreads();
  float inv = 1.0f / sa[0];
  bf16x8 o8;
#pragma unroll
  for (int j = 0; j < 8; ++j) o8[j] = (bf16_t)(v[j] * inv);
  *(bf16x8*)(P + (size_t)row * 2048 + t * 8) = o8;
}

// ---------------- host ----------------
extern "C" void kernel_launch(void* const* d_in, const int* in_sizes, int n_in,
                              void* d_out, int out_size, void* d_ws, size_t ws_size,
                              hipStream_t stream) {
  const float* x     = (const float*)d_in[0];
  const float* ln1_g = (const float*)d_in[1];
  const float* ln1_b = (const float*)d_in[2];
  const float* ln2_g = (const float*)d_in[3];
  const float* ln2_b = (const float*)d_in[4];
  const float* qkv_w = (const float*)d_in[5];
  const float* qkv_b = (const float*)d_in[6];
  const float* out_w = (const float*)d_in[7];
  const float* out_b = (const float*)d_in[8];
  const float* w1    = (const float*)d_in[9];
  const float* b1    = (const float*)d_in[10];
  const float* w2    = (const float*)d_in[11];
  const float* b2    = (const float*)d_in[12];
  float* out = (float*)d_out;
  char* ws = (char*)d_ws;

  // workspace layout (bytes), total 268,435,456
  bf16_t* qkv_wT = (bf16_t*)(ws + 0);           // [6144][2048] bf16 = 25,165,824
  bf16_t* out_wT = (bf16_t*)(ws + 25165824);    // [2048][2048] bf16 =  8,388,608
  bf16_t* w1T    = (bf16_t*)(ws + 33554432);    // [8192][2048] bf16 = 33,554,432
  bf16_t* w2T    = (bf16_t*)(ws + 67108864);    // [2048][8192] bf16 = 33,554,432
  bf16_t* h_bf   = (bf16_t*)(ws + 100663296);   // [4096][2048] bf16 = 16,777,216
  bf16_t* qkv_bf = (bf16_t*)(ws + 117440512);   // [4096][6144] bf16 = 50,331,648
  float*  scores = (float*)(ws + 167772160);    // [2][2048][2048] f32 = 33,554,432
  bf16_t* attn_bf= (bf16_t*)(ws + 201326592);   // [2][2048][2048] bf16 = 16,777,216
  bf16_t* ao_bf  = (bf16_t*)(ws + 218103808);   // [4096][2048] bf16 = 16,777,216
  float*  x2     = (float*)(ws + 234881024);    // [4096][2048] f32 = 33,554,432
  bf16_t* mid_bf = (bf16_t*)(ws + 117440512);   // alias qkv_bf+scores (dead by MLP1)
  bf16_t* Vt     = (bf16_t*)(ws + 234881024);   // aliases x2 (dead by step 8)
  float*  part0  = (float*)(ws + 0);            // [4096][2048] f32, aliases qkv_wT+out_wT... (dead by MLP2)
  float*  part1  = (float*)(ws + 201326592);    // [4096][2048] f32, aliases attn_bf+ao_bf (dead by MLP2)

  const float inv_sqrt_h = 0.022097086912079608f; // 1/sqrt(2048)

  // 1) weight transposes (fp32 -> bf16 [N][K])
  tb_transpose_cast<<<dim3(6144 / 32, 2048 / 32), 256, 0, stream>>>(qkv_w, qkv_wT, 2048, 6144);
  tb_transpose_cast<<<dim3(2048 / 32, 2048 / 32), 256, 0, stream>>>(out_w, out_wT, 2048, 2048);
  tb_transpose_cast<<<dim3(8192 / 32, 2048 / 32), 256, 0, stream>>>(w1, w1T, 2048, 8192);
  tb_transpose_cast<<<dim3(2048 / 32, 8192 / 32), 256, 0, stream>>>(w2, w2T, 8192, 2048);

  // 2) LN1: x -> h_bf
  tb_layernorm<<<4096, 256, 0, stream>>>(x, ln1_g, ln1_b, h_bf);

  // 3) QKV: h_bf @ qkv_w + qkv_b -> qkv_bf  (M=4096, N=6144, K=2048)
  tb_gemm8<EPI_BF16_BIAS><<<dim3(24, 16, 1), 512, 0, stream>>>(
      h_bf, 2048, 0, qkv_wT, 2048, 0, qkv_b, nullptr, qkv_bf, 6144, 0, 2048, 1.0f);

  // 4) V transpose: qkv_bf[z][t][4096+h] -> Vt[z][h][t]
  tb_transpose_bf16<<<dim3(64, 64, 2), 256, 0, stream>>>(
      qkv_bf + 4096, 6144, 2048LL * 6144, Vt, 2048, 2048LL * 2048);

  // 5) scores[z] = q[z] @ k[z]^T / sqrt(H)  (M=N=K=2048, z=2)
  tb_gemm8<EPI_F32_SCALE><<<dim3(8, 8, 2), 512, 0, stream>>>(
      qkv_bf, 6144, 2048LL * 6144, qkv_bf + 2048, 6144, 2048LL * 6144,
      nullptr, nullptr, scores, 2048, 2048LL * 2048, 2048, inv_sqrt_h);

  // 6) softmax rows -> attn_bf
  tb_softmax<<<4096, 256, 0, stream>>>(scores, attn_bf);

  // 7) PV: attn[z] @ v[z] -> ao_bf ; B = Vt[z] is [N=h][K=t]
  tb_gemm8<EPI_BF16><<<dim3(8, 8, 2), 512, 0, stream>>>(
      attn_bf, 2048, 2048LL * 2048, Vt, 2048, 2048LL * 2048,
      nullptr, nullptr, ao_bf, 2048, 2048LL * 2048, 2048, 1.0f);

  // 8) out-proj + residual: x2 = x + ao_bf @ out_w + out_b  (M=4096, N=2048, K=2048)
  tb_gemm8<EPI_F32_BIAS_RES><<<dim3(8, 16, 1), 512, 0, stream>>>(
      ao_bf, 2048, 0, out_wT, 2048, 0, out_b, x, x2, 2048, 0, 2048, 1.0f);

  // 9) LN2: x2 -> h_bf (reuse)
  tb_layernorm<<<4096, 256, 0, stream>>>(x2, ln2_g, ln2_b, h_bf);

  // 10) MLP1 + GELU: mid_bf = gelu(h_bf @ w1 + b1)  (M=4096, N=8192, K=2048)
  tb_gemm8<EPI_BF16_BIAS_GELU><<<dim3(32, 16, 1), 512, 0, stream>>>(
      h_bf, 2048, 0, w1T, 2048, 0, b1, nullptr, mid_bf, 8192, 0, 2048, 1.0f);

  // 11) MLP2 split-K x2: part_z = mid_bf[:, z*4096:] @ w2T[:, z*4096:]^T  (256 blocks)
  tb_gemm8<EPI_F32_SCALE><<<dim3(8, 16, 2), 512, 0, stream>>>(
      mid_bf, 8192, 4096, w2T, 8192, 4096,
      nullptr, nullptr, part0, 2048, 50331648LL, 4096, 1.0f);

  // 12) combine: out = x2 + part0 + part1 + b2
  tb_combine<<<8192, 256, 0, stream>>>(x2, part0, part1, b2, out);
}